// Round 18
// baseline (513.015 us; speedup 1.0000x reference)
//
#include <hip/hip_runtime.h>
#include <hip/hip_bf16.h>
#include <math.h>

#define D_MODEL 768
#define T_SEQ   1024
#define B_BATCH 16
#define MLP_DIM 3072
#define M_ROWS  (B_BATCH * T_SEQ)   // 16384

typedef __attribute__((ext_vector_type(8))) __bf16          bf16x8;
typedef __attribute__((ext_vector_type(4))) __bf16          bf16x4;
typedef __attribute__((ext_vector_type(4))) float           f32x4;

__device__ __forceinline__ float bf2f(unsigned short u) {
  union { unsigned int u; float f; } w; w.u = ((unsigned int)u) << 16; return w.f;
}
__device__ __forceinline__ unsigned short f2bf(float f) {
  union { float f; unsigned int u; } w; w.f = f;
  unsigned int r = (w.u + 0x7fffu + ((w.u >> 16) & 1u)) >> 16;
  return (unsigned short)r;
}
// fast GELU: tanh-form, x / (1 + 2^(x*(a + b x^2))), |err| <= ~3e-3 vs erf
__device__ __forceinline__ float gelu_f(float x) {
  const float a2 = -2.302283f, b2 = -0.102947f;
  return x / (1.0f + exp2f(x * fmaf(b2, x * x, a2)));
}
// async global->LDS, 16B per lane; LDS dest = wave-uniform base + lane*16
__device__ __forceinline__ void gload16(const void* g, void* l) {
  __builtin_amdgcn_global_load_lds(
      (const __attribute__((address_space(1))) unsigned int*)g,
      (__attribute__((address_space(3))) unsigned int*)l, 16, 0, 0);
}

// ------- weight transpose+convert: dst[N=C][K=R] bf16 = src[R][C] f32 ------
__global__ void wtr_k(const float* __restrict__ src,
                      unsigned short* __restrict__ dst, int R, int C) {
  __shared__ float t[32][33];
  const int c0 = blockIdx.x * 32, r0 = blockIdx.y * 32;
  const int tx = threadIdx.x, ty = threadIdx.y;
  #pragma unroll
  for (int j = 0; j < 32; j += 8)
    t[ty + j][tx] = src[(size_t)(r0 + ty + j) * C + (c0 + tx)];
  __syncthreads();
  #pragma unroll
  for (int j = 0; j < 32; j += 8)
    dst[(size_t)(c0 + ty + j) * R + (r0 + tx)] = f2bf(t[tx][ty + j]);
}

// ------- concat 3 bias vectors of 768 f32 --------------------------------
__global__ void bcat_k(const float* __restrict__ a, const float* __restrict__ b,
                       const float* __restrict__ c, float* __restrict__ o) {
  const int i = blockIdx.x * 256 + threadIdx.x;
  if (i < 768) { o[i] = a[i]; o[i + 768] = b[i]; o[i + 1536] = c[i]; }
}

// ---------- fused LayerNorm (stats + apply), one block per row -------------
template<int SRC_F32>
__global__ __launch_bounds__(256) void ln_k(const void* __restrict__ src,
    const float* __restrict__ g, const float* __restrict__ b,
    unsigned short* __restrict__ out) {
  const int row = blockIdx.x, tid = threadIdx.x;
  const size_t base = (size_t)row * D_MODEL;
  float v[3];
  #pragma unroll
  for (int i = 0; i < 3; ++i) {
    const int c = tid + (i << 8);
    v[i] = SRC_F32 ? ((const float*)src)[base + c]
                   : bf2f(((const unsigned short*)src)[base + c]);
  }
  float s  = v[0] + v[1] + v[2];
  float sq = v[0]*v[0] + v[1]*v[1] + v[2]*v[2];
  #pragma unroll
  for (int m = 32; m; m >>= 1) { s += __shfl_xor(s, m); sq += __shfl_xor(sq, m); }
  __shared__ float ps[4], pq[4];
  if ((tid & 63) == 0) { ps[tid >> 6] = s; pq[tid >> 6] = sq; }
  __syncthreads();
  s  = ps[0] + ps[1] + ps[2] + ps[3];
  sq = pq[0] + pq[1] + pq[2] + pq[3];
  const float mu  = s * (1.0f / 768.0f);
  const float var = sq * (1.0f / 768.0f) - mu * mu;
  const float inv = rsqrtf(var + 1e-5f);
  #pragma unroll
  for (int i = 0; i < 3; ++i) {
    const int c = tid + (i << 8);
    out[base + c] = f2bf((v[i] - mu) * inv * g[c] + b[c]);
  }
}

// ---- GEMM (large): 256x256 tile, BK=64, 8 waves, dbuf 128KB, 4-phase ------
// (round-13/17 structure, best measured). Counted vmcnt(2) once per tile.
// EP 1: gelu->bf16 | EP 5: fused QKV split store (outv=q, residv=k, aux=v^T)
template<int EP>
__global__ __launch_bounds__(512) void gemm_k(
    const unsigned short* __restrict__ Au, const unsigned short* __restrict__ Btu,
    const float* __restrict__ bias, void* __restrict__ outv,
    const void* __restrict__ residv, void* __restrict__ aux,
    int M, int N, int K, int cgrp) {
  __shared__ __align__(16) __bf16 SMEM[2 * 32768];          // 128 KB
  const __bf16* A  = (const __bf16*)Au;
  const __bf16* Bt = (const __bf16*)Btu;
  const int tid = threadIdx.x;
  const int lane = tid & 63, w = tid >> 6;      // 8 waves
  const int wr = w >> 2, wc = w & 3;            // 2 x 4 wave grid
  const int lr = lane & 15, lg = lane >> 4;
  const int gx = gridDim.x;
  const int bid = blockIdx.y * gx + blockIdx.x;
  const int xcd = bid & 7, idx = bid >> 3;
  const int rpx = gx >> 3;
  const int gsz = rpx * cgrp;
  const int grp = idx / gsz, rem = idx - grp * gsz;
  const int rb = rem / cgrp, cc2 = rem - rb * cgrp + grp * cgrp;
  const int brow = (xcd * rpx + rb) * 256;
  const int bcol = cc2 * 256;

  f32x4 acc[8][4];
  #pragma unroll
  for (int m = 0; m < 8; ++m)
    #pragma unroll
    for (int n = 0; n < 4; ++n) acc[m][n] = (f32x4){0.f, 0.f, 0.f, 0.f};

  const int rrs = lane >> 2;
  const int ccs = (lane & 3) << 3;
  const int csw = ccs ^ ((((lane >> 3) & 3)) << 3);
  const __bf16* sA[4]; const __bf16* sB[4]; int dA[4], dB[4];
  #pragma unroll
  for (int g = 0; g < 4; ++g) {
    const int s = g * 8 + w;
    const int rsrc = (s >> 1) * 16 + rrs;
    const int csrc = (s & 1) * 32 + csw;
    sA[g] = A  + (size_t)(brow + rsrc) * K + csrc;
    sB[g] = Bt + (size_t)(bcol + rsrc) * K + csrc;
    dA[g] = s * 512;
    dB[g] = 16384 + s * 512;
  }

#define STAGE2_(nbb_, k0_, g_) do {                         \
    gload16(sA[g_] + (k0_), &SMEM[(nbb_) + dA[g_]]);        \
    gload16(sB[g_] + (k0_), &SMEM[(nbb_) + dB[g_]]);        \
  } while (0)

  const int rbase = lr * 32 + ((lg << 3) ^ (((lr >> 1) & 3) << 3));

  #pragma unroll
  for (int g = 0; g < 4; ++g) STAGE2_(0, 0, g);

  int cur = 0;
  for (int k0 = 0; k0 < K; k0 += 64, cur ^= 1) {
    const int bb  = cur * 32768;
    const int nbb = (cur ^ 1) * 32768;
    const bool pf = (k0 + 64 < K);
    bf16x8 af0[4][2], af1[4][2], bfr[4][2];
    // P1
    if (pf) {
      STAGE2_(nbb, k0 + 64, 0);
      asm volatile("s_waitcnt vmcnt(2)" ::: "memory");
    } else {
      asm volatile("s_waitcnt vmcnt(0)" ::: "memory");
    }
    __builtin_amdgcn_s_barrier();
    __builtin_amdgcn_sched_barrier(0);
    #pragma unroll
    for (int ml = 0; ml < 4; ++ml)
      #pragma unroll
      for (int kk = 0; kk < 2; ++kk)
        af0[ml][kk] = *(const bf16x8*)(&SMEM[bb + ((wr*8 + ml)*2 + kk)*512 + rbase]);
    #pragma unroll
    for (int n = 0; n < 2; ++n)
      #pragma unroll
      for (int kk = 0; kk < 2; ++kk)
        bfr[n][kk] = *(const bf16x8*)(&SMEM[bb + 16384 + ((wc*4 + n)*2 + kk)*512 + rbase]);
    asm volatile("s_waitcnt lgkmcnt(0)" ::: "memory");
    __builtin_amdgcn_sched_barrier(0);
    __builtin_amdgcn_s_setprio(1);
    #pragma unroll
    for (int ml = 0; ml < 4; ++ml)
      #pragma unroll
      for (int n = 0; n < 2; ++n) {
        acc[ml][n] = __builtin_amdgcn_mfma_f32_16x16x32_bf16(af0[ml][0], bfr[n][0], acc[ml][n], 0, 0, 0);
        acc[ml][n] = __builtin_amdgcn_mfma_f32_16x16x32_bf16(af0[ml][1], bfr[n][1], acc[ml][n], 0, 0, 0);
      }
    __builtin_amdgcn_s_setprio(0);
    __builtin_amdgcn_s_barrier();
    // P2
    #pragma unroll
    for (int n = 2; n < 4; ++n)
      #pragma unroll
      for (int kk = 0; kk < 2; ++kk)
        bfr[n][kk] = *(const bf16x8*)(&SMEM[bb + 16384 + ((wc*4 + n)*2 + kk)*512 + rbase]);
    if (pf) STAGE2_(nbb, k0 + 64, 1);
    asm volatile("s_waitcnt lgkmcnt(0)" ::: "memory");
    __builtin_amdgcn_sched_barrier(0);
    __builtin_amdgcn_s_setprio(1);
    #pragma unroll
    for (int ml = 0; ml < 4; ++ml)
      #pragma unroll
      for (int n = 2; n < 4; ++n) {
        acc[ml][n] = __builtin_amdgcn_mfma_f32_16x16x32_bf16(af0[ml][0], bfr[n][0], acc[ml][n], 0, 0, 0);
        acc[ml][n] = __builtin_amdgcn_mfma_f32_16x16x32_bf16(af0[ml][1], bfr[n][1], acc[ml][n], 0, 0, 0);
      }
    __builtin_amdgcn_s_setprio(0);
    __builtin_amdgcn_s_barrier();
    // P3
    #pragma unroll
    for (int ml = 0; ml < 4; ++ml)
      #pragma unroll
      for (int kk = 0; kk < 2; ++kk)
        af1[ml][kk] = *(const bf16x8*)(&SMEM[bb + ((wr*8 + 4 + ml)*2 + kk)*512 + rbase]);
    if (pf) STAGE2_(nbb, k0 + 64, 2);
    asm volatile("s_waitcnt lgkmcnt(0)" ::: "memory");
    __builtin_amdgcn_sched_barrier(0);
    __builtin_amdgcn_s_setprio(1);
    #pragma unroll
    for (int ml = 0; ml < 4; ++ml)
      #pragma unroll
      for (int n = 0; n < 2; ++n) {
        acc[4+ml][n] = __builtin_amdgcn_mfma_f32_16x16x32_bf16(af1[ml][0], bfr[n][0], acc[4+ml][n], 0, 0, 0);
        acc[4+ml][n] = __builtin_amdgcn_mfma_f32_16x16x32_bf16(af1[ml][1], bfr[n][1], acc[4+ml][n], 0, 0, 0);
      }
    __builtin_amdgcn_s_setprio(0);
    __builtin_amdgcn_s_barrier();
    // P4
    if (pf) STAGE2_(nbb, k0 + 64, 3);
    __builtin_amdgcn_s_setprio(1);
    #pragma unroll
    for (int ml = 0; ml < 4; ++ml)
      #pragma unroll
      for (int n = 2; n < 4; ++n) {
        acc[4+ml][n] = __builtin_amdgcn_mfma_f32_16x16x32_bf16(af1[ml][0], bfr[n][0], acc[4+ml][n], 0, 0, 0);
        acc[4+ml][n] = __builtin_amdgcn_mfma_f32_16x16x32_bf16(af1[ml][1], bfr[n][1], acc[4+ml][n], 0, 0, 0);
      }
    __builtin_amdgcn_s_setprio(0);
    __builtin_amdgcn_s_barrier();
  }
#undef STAGE2_

  const int seg = (EP == 5) ? (bcol / 768) : 0;
  unsigned short* qkvp = nullptr;
  if (EP == 5)
    qkvp = (seg == 0) ? (unsigned short*)outv
         : (seg == 1) ? (unsigned short*)residv : (unsigned short*)aux;

  if (EP == 5 && seg == 2) {
    #pragma unroll
    for (int n = 0; n < 4; ++n) {
      const int col = bcol + wc*64 + n*16 + lr;
      const float bv = bias[col];
      const int colLv = col - 1536;
      #pragma unroll
      for (int m = 0; m < 8; ++m) {
        const int row0 = brow + wr*128 + m*16 + lg*4;
        #pragma unroll
        for (int r2 = 0; r2 < 4; ++r2) {
          const int gr = row0 + r2;
          qkvp[(((size_t)(gr >> 10) * D_MODEL + colLv) << 10) + (gr & 1023)] =
              f2bf(acc[m][n][r2] + bv);
        }
      }
    }
  } else {
    float* Ep = (float*)SMEM + w * 1280;
    #pragma unroll
    for (int m = 0; m < 8; ++m) {
      #pragma unroll
      for (int n = 0; n < 4; ++n) {
        const int col = bcol + wc*64 + n*16 + lr;
        const float bv = bias[col];
        f32x4 st;
        #pragma unroll
        for (int r2 = 0; r2 < 4; ++r2) {
          float v = acc[m][n][r2] + bv;
          if (EP == 1) v = gelu_f(v);
          st[r2] = v;
        }
        *(f32x4*)(Ep + (n*16 + lr) * 20 + lg*4) = st;
      }
      #pragma unroll
      for (int i2 = 0; i2 < 2; ++i2) {
        const int rowL = i2*8 + (lane >> 3);
        const int colL = (lane & 7) * 8;
        const int grow = brow + wr*128 + m*16 + rowL;
        const int gcol = bcol + wc*64 + colL;
        float v[8];
        #pragma unroll
        for (int j = 0; j < 8; ++j) v[j] = Ep[(colL + j) * 20 + rowL];
        const size_t o = (size_t)grow * N + gcol;
        if (EP == 5) {
          bf16x8 ov;
          #pragma unroll
          for (int j = 0; j < 8; ++j) ov[j] = (__bf16)v[j];
          *(bf16x8*)((__bf16*)qkvp + (size_t)grow * 768 + (gcol - seg * 768)) = ov;
        } else {               // EP 0 / 1
          bf16x8 ov;
          #pragma unroll
          for (int j = 0; j < 8; ++j) ov[j] = (__bf16)v[j];
          *(bf16x8*)((__bf16*)outv + o) = ov;
        }
      }
    }
  }
}

// ---- GEMM (small-N): 128x128 tile, BK=32, 4 waves, 32KB LDS, 2-phase ------
// (round-11 proven structure; dense co-residency for N=768 GEMMs.)
// EP 2: +resid(f32) -> bf16 | EP 3: gelu + resid(bf16) -> f32 (final output)
template<int EP>
__global__ __launch_bounds__(256) void gemm_s(
    const unsigned short* __restrict__ Au, const unsigned short* __restrict__ Btu,
    const float* __restrict__ bias, void* __restrict__ outv,
    const void* __restrict__ residv, int M, int N, int K, int cgrp) {
  __shared__ __align__(16) __bf16 SMEM[2 * 2 * 128 * 32];   // 32 KB
  auto As = (__bf16 (*)[128][32])(SMEM);
  auto Bs = (__bf16 (*)[128][32])(SMEM + 2 * 128 * 32);
  const __bf16* A  = (const __bf16*)Au;
  const __bf16* Bt = (const __bf16*)Btu;
  const int tid = threadIdx.x;
  const int lane = tid & 63, wid = tid >> 6;
  const int wr = wid >> 1, wc = wid & 1;
  const int gx = gridDim.x;
  const int bid = blockIdx.y * gx + blockIdx.x;
  const int xcd = bid & 7, idx = bid >> 3;
  const int rpx = gx >> 3;
  const int gsz = rpx * cgrp;
  const int grp = idx / gsz, rem = idx - grp * gsz;
  const int rb = rem / cgrp, cc2 = rem - rb * cgrp + grp * cgrp;
  const int brow = (xcd * rpx + rb) * 128;
  const int bcol = cc2 * 128;
  const int lr = lane & 15, lg = lane >> 4;
  f32x4 acc[4][4];
  #pragma unroll
  for (int m = 0; m < 4; ++m)
    #pragma unroll
    for (int n = 0; n < 4; ++n) acc[m][n] = (f32x4){0.f, 0.f, 0.f, 0.f};

  const int srow = (wid << 5) + (lane >> 2);
  const int scol = (lane & 3) << 3;
  const __bf16* gA = A  + (size_t)(brow + srow) * K + scol;
  const __bf16* gB = Bt + (size_t)(bcol + srow) * K + scol;

#define STAGE_(buf_, k0_) do {                                        \
    gload16(gA + (k0_),                   &As[buf_][(wid << 5)][0]);  \
    gload16(gA + (k0_) + 16 * (size_t)K,  &As[buf_][(wid << 5) + 16][0]); \
    gload16(gB + (k0_),                   &Bs[buf_][(wid << 5)][0]);  \
    gload16(gB + (k0_) + 16 * (size_t)K,  &Bs[buf_][(wid << 5) + 16][0]); \
  } while (0)

  STAGE_(0, 0);
  int cur = 0;
  for (int k0 = 0; k0 < K; k0 += 32, cur ^= 1) {
    if (k0 + 32 < K) {
      STAGE_(cur ^ 1, k0 + 32);
      asm volatile("s_waitcnt vmcnt(4)" ::: "memory");
    } else {
      asm volatile("s_waitcnt vmcnt(0)" ::: "memory");
    }
    __builtin_amdgcn_s_barrier();
    __builtin_amdgcn_sched_barrier(0);
    bf16x8 af[4], bfr[4];
    #pragma unroll
    for (int m = 0; m < 4; ++m) af[m]  = *(const bf16x8*)(&As[cur][wr*64 + m*16 + lr][lg*8]);
    #pragma unroll
    for (int n = 0; n < 4; ++n) bfr[n] = *(const bf16x8*)(&Bs[cur][wc*64 + n*16 + lr][lg*8]);
    asm volatile("s_waitcnt lgkmcnt(0)" ::: "memory");
    __builtin_amdgcn_sched_barrier(0);
    __builtin_amdgcn_s_setprio(1);
    #pragma unroll
    for (int m = 0; m < 4; ++m)
      #pragma unroll
      for (int n = 0; n < 4; ++n)
        acc[m][n] = __builtin_amdgcn_mfma_f32_16x16x32_bf16(af[m], bfr[n], acc[m][n], 0, 0, 0);
    __builtin_amdgcn_s_setprio(0);
    __builtin_amdgcn_s_barrier();
  }
#undef STAGE_

  // coalesced bounce epilogue: per-wave f32 tile [64 col][20 row]
  float* Ep = (float*)SMEM + wid * 1280;
  #pragma unroll
  for (int p = 0; p < 4; ++p) {
    #pragma unroll
    for (int n = 0; n < 4; ++n) {
      const int col = bcol + wc*64 + n*16 + lr;
      const float bv = bias[col];
      f32x4 st;
      #pragma unroll
      for (int r2 = 0; r2 < 4; ++r2) {
        float v = acc[p][n][r2] + bv;
        if (EP == 3) v = gelu_f(v);
        st[r2] = v;
      }
      *(f32x4*)(Ep + (n*16 + lr) * 20 + lg*4) = st;
    }
    #pragma unroll
    for (int i2 = 0; i2 < 2; ++i2) {
      const int rowL = i2*8 + (lane >> 3);
      const int colL = (lane & 7) * 8;
      const int grow = brow + wr*64 + p*16 + rowL;
      const int gcol = bcol + wc*64 + colL;
      float v[8];
      #pragma unroll
      for (int j = 0; j < 8; ++j) v[j] = Ep[(colL + j) * 20 + rowL];
      const size_t o = (size_t)grow * N + gcol;
      if (EP == 3) {                 // gelu already applied; + resid(bf16) -> f32
        const bf16x8 rv = *(const bf16x8*)((const __bf16*)residv + o);
        float* op = (float*)outv + o;
        float4 o0, o1;
        o0.x = v[0] + (float)rv[0]; o0.y = v[1] + (float)rv[1];
        o0.z = v[2] + (float)rv[2]; o0.w = v[3] + (float)rv[3];
        o1.x = v[4] + (float)rv[4]; o1.y = v[5] + (float)rv[5];
        o1.z = v[6] + (float)rv[6]; o1.w = v[7] + (float)rv[7];
        *(float4*)op = o0; *(float4*)(op + 4) = o1;
      } else {                       // EP 2: + resid(f32) -> bf16
        const float* rp = (const float*)residv + o;
        const float4 r0 = *(const float4*)rp, r1 = *(const float4*)(rp + 4);
        bf16x8 ov;
        ov[0] = (__bf16)(v[0] + r0.x); ov[1] = (__bf16)(v[1] + r0.y);
        ov[2] = (__bf16)(v[2] + r0.z); ov[3] = (__bf16)(v[3] + r0.w);
        ov[4] = (__bf16)(v[4] + r1.x); ov[5] = (__bf16)(v[5] + r1.y);
        ov[6] = (__bf16)(v[6] + r1.z); ov[7] = (__bf16)(v[7] + r1.w);
        *(bf16x8*)((__bf16*)outv + o) = ov;
      }
    }
  }
}

// ---------------- flash attention: 768 blocks, XCD-sequential bh -----------
__global__ __launch_bounds__(512) void attn_k(
    const unsigned short* qu, const unsigned short* __restrict__ ku,
    const unsigned short* __restrict__ vtu, unsigned short* attn) {
  __shared__ __align__(16) __bf16 Kl[64][72];
  __shared__ __align__(16) __bf16 Vl[64][72];
  __shared__ __align__(16) __bf16 Pl[8][16][72];
  const __bf16* qg  = (const __bf16*)qu;
  const __bf16* kg  = (const __bf16*)ku;
  const __bf16* vtg = (const __bf16*)vtu;
  const int bid = blockIdx.x;
  const int xcd = bid & 7, idx = bid >> 3;
  const int bh = xcd * 24 + (idx >> 2);
  const int b = bh / 12, h = bh % 12;
  const int q0 = (idx & 3) * 256;
  const int tid = threadIdx.x, lane = tid & 63, w = tid >> 6;
  const int lr = lane & 15, lg = lane >> 4;
  const float scale = 0.03608439182435161f; // 1/sqrt(768)

  bf16x8 qa[2][2];
  #pragma unroll
  for (int g = 0; g < 2; ++g) {
    const int qrow = b * T_SEQ + q0 + w * 32 + g * 16 + lr;
    const __bf16* qp = qg + (size_t)qrow * D_MODEL + h * 64 + lg * 8;
    qa[g][0] = *(const bf16x8*)(qp);
    qa[g][1] = *(const bf16x8*)(qp + 32);
  }

  const __bf16* kb = kg  + (size_t)b * T_SEQ * D_MODEL + h * 64;
  const __bf16* vb = vtg + ((size_t)b * D_MODEL + h * 64) * T_SEQ;

  f32x4 o[2][4];
  float m_run[2] = {-1e30f, -1e30f}, l_run[2] = {0.f, 0.f};
  #pragma unroll
  for (int g = 0; g < 2; ++g)
    #pragma unroll
    for (int m = 0; m < 4; ++m) o[g][m] = (f32x4){0.f, 0.f, 0.f, 0.f};

  for (int kv0 = 0; kv0 < T_SEQ; kv0 += 64) {
    __syncthreads();
    {
      const int r = tid >> 3, c = (tid & 7) << 3;
      *(bf16x8*)(&Kl[r][c]) = *(const bf16x8*)(kb + (size_t)(kv0 + r) * D_MODEL + c);
      *(bf16x8*)(&Vl[r][c]) = *(const bf16x8*)(vb + (size_t)r * T_SEQ + kv0 + c);
    }
    __syncthreads();

    #pragma unroll
    for (int g = 0; g < 2; ++g) {
      f32x4 s[4];
      __builtin_amdgcn_s_setprio(1);
      #pragma unroll
      for (int m = 0; m < 4; ++m) {
        s[m] = (f32x4){0.f, 0.f, 0.f, 0.f};
        const bf16x8 kf0 = *(const bf16x8*)(&Kl[m*16 + lr][lg*8]);
        const bf16x8 kf1 = *(const bf16x8*)(&Kl[m*16 + lr][32 + lg*8]);
        s[m] = __builtin_amdgcn_mfma_f32_16x16x32_bf16(kf0, qa[g][0], s[m], 0, 0, 0);
        s[m] = __builtin_amdgcn_mfma_f32_16x16x32_bf16(kf1, qa[g][1], s[m], 0, 0, 0);
      }
      __builtin_amdgcn_s_setprio(0);
      float sv[4][4], tm = -1e30f;
      #pragma unroll
      for (int m = 0; m < 4; ++m)
        #pragma unroll
        for (int r = 0; r < 4; ++r) {
          sv[m][r] = s[m][r] * scale;
          tm = fmaxf(tm, sv[m][r]);
        }
      tm = fmaxf(tm, __shfl_xor(tm, 16));
      tm = fmaxf(tm, __shfl_xor(tm, 32));
      const float mn = fmaxf(m_run[g], tm);
      const float sc = __expf(m_run[g] - mn);
      float ts = 0.f;
      bf16x4 pk[4];
      #pragma unroll
      for (int m = 0; m < 4; ++m)
        #pragma unroll
        for (int r = 0; r < 4; ++r) {
          const float pp = __expf(sv[m][r] - mn);
          ts += pp;
          pk[m][r] = (__bf16)pp;
        }
      ts += __shfl_xor(ts, 16);
      ts += __shfl_xor(ts, 32);
      l_run[g] = l_run[g] * sc + ts;
      m_run[g] = mn;
      #pragma unroll
      for (int m = 0; m < 4; ++m)
        #pragma unroll
        for (int r = 0; r < 4; ++r) o[g][m][r] *= sc;
      #pragma unroll
      for (int m = 0; m < 4; ++m)
        *(bf16x4*)(&Pl[w][lr][16*m + 4*lg]) = pk[m];
      const bf16x8 pf0 = *(const bf16x8*)(&Pl[w][lr][lg*8]);
      const bf16x8 pf1 = *(const bf16x8*)(&Pl[w][lr][32 + lg*8]);
      __builtin_amdgcn_s_setprio(1);
      #pragma unroll
      for (int m = 0; m < 4; ++m) {
        const bf16x8 vf0 = *(const bf16x8*)(&Vl[m*16 + lr][lg*8]);
        const bf16x8 vf1 = *(const bf16x8*)(&Vl[m*16 + lr][32 + lg*8]);
        o[g][m] = __builtin_amdgcn_mfma_f32_16x16x32_bf16(vf0, pf0, o[g][m], 0, 0, 0);
        o[g][m] = __builtin_amdgcn_mfma_f32_16x16x32_bf16(vf1, pf1, o[g][m], 0, 0, 0);
      }
      __builtin_amdgcn_s_setprio(0);
    }
  }

  #pragma unroll
  for (int g = 0; g < 2; ++g) {
    const float inv = 1.0f / l_run[g];
    const int qrow = b * T_SEQ + q0 + w * 32 + g * 16 + lr;
    unsigned short* op = attn + (size_t)qrow * D_MODEL + h * 64;
    #pragma unroll
    for (int m = 0; m < 4; ++m) {
      bf16x4 ov;
      #pragma unroll
      for (int r = 0; r < 4; ++r) ov[r] = (__bf16)(o[g][m][r] * inv);
      *(bf16x4*)(op + 16*m + 4*lg) = ov;
    }
  }
}

// ---------------------------------------------------------------------------
extern "C" void kernel_launch(void* const* d_in, const int* in_sizes, int n_in,
                              void* d_out, int out_size, void* d_ws, size_t ws_size,
                              hipStream_t stream) {
  const float* x   = (const float*)d_in[0];
  const float* Wq  = (const float*)d_in[1];
  const float* bq  = (const float*)d_in[2];
  const float* Wk  = (const float*)d_in[3];
  const float* bk  = (const float*)d_in[4];
  const float* Wv  = (const float*)d_in[5];
  const float* bv  = (const float*)d_in[6];
  const float* Wo  = (const float*)d_in[7];
  const float* bo  = (const float*)d_in[8];
  const float* g1  = (const float*)d_in[9];
  const float* bt1 = (const float*)d_in[10];
  const float* g2  = (const float*)d_in[11];
  const float* bt2 = (const float*)d_in[12];
  const float* W1  = (const float*)d_in[13];
  const float* bb1 = (const float*)d_in[14];
  const float* W2  = (const float*)d_in[15];
  const float* bb2 = (const float*)d_in[16];

  const size_t SZ = (size_t)M_ROWS * D_MODEL * 2;   // 25,165,824
  char* wp = (char*)d_ws;
  unsigned short* wqkvT = (unsigned short*)wp; wp += (size_t)2304 * 768 * 2;
  unsigned short* woT   = (unsigned short*)wp; wp += (size_t)768 * 768 * 2;
  unsigned short* w1T   = (unsigned short*)wp; wp += (size_t)768 * 3072 * 2;
  unsigned short* w2T   = (unsigned short*)wp; wp += (size_t)768 * 3072 * 2;
  float*          bqkv  = (float*)wp;          wp += ((size_t)2304 * 4 + 255) & ~(size_t)255;
  unsigned short* kbuf  = (unsigned short*)wp; wp += SZ;   // k -> res2
  unsigned short* vtb   = (unsigned short*)wp;             // vT -> hid
  unsigned short* res2  = kbuf;
  unsigned short* hid   = vtb;
  const size_t avail = ws_size - (size_t)(wp - (char*)d_ws);
  const int nch = (avail >= (size_t)M_ROWS * MLP_DIM * 2) ? 1
                : (avail >= (size_t)(M_ROWS / 2) * MLP_DIM * 2) ? 2 : 4;

  unsigned short* qd = (unsigned short*)d_out;             // bf16 lo half
  unsigned short* h1 = qd + (size_t)M_ROWS * D_MODEL;      // bf16 hi half
  unsigned short* h2 = h1;

  const dim3 tb(32, 8, 1);
  wtr_k<<<dim3(24, 24), tb, 0, stream>>>(Wq, wqkvT, 768, 768);
  wtr_k<<<dim3(24, 24), tb, 0, stream>>>(Wk, wqkvT + (size_t)768 * 768, 768, 768);
  wtr_k<<<dim3(24, 24), tb, 0, stream>>>(Wv, wqkvT + (size_t)1536 * 768, 768, 768);
  wtr_k<<<dim3(24, 24), tb, 0, stream>>>(Wo, woT, 768, 768);
  wtr_k<<<dim3(96, 24), tb, 0, stream>>>(W1, w1T, 768, 3072);
  wtr_k<<<dim3(24, 96), tb, 0, stream>>>(W2, w2T, 3072, 768);
  bcat_k<<<3, 256, 0, stream>>>(bq, bk, bv, bqkv);

  ln_k<1><<<M_ROWS, 256, 0, stream>>>(x, g1, bt1, h1);

  gemm_k<5><<<dim3(64, 9), 512, 0, stream>>>(h1, wqkvT, bqkv, qd, kbuf, vtb,
                                             M_ROWS, 2304, 768, 9);

  attn_k<<<dim3(768), 512, 0, stream>>>(qd, kbuf, vtb, qd);

  gemm_s<2><<<dim3(128, 6), 256, 0, stream>>>(qd, woT, bo, res2, x,
                                              M_ROWS, 768, 768, 3);

  ln_k<0><<<M_ROWS, 256, 0, stream>>>(res2, g2, bt2, h2);

  const int CH = M_ROWS / nch;
  for (int c = 0; c < nch; ++c) {
    const size_t ro = (size_t)c * CH;
    gemm_k<1><<<dim3(CH / 256, 12), 512, 0, stream>>>(h2 + ro * 768, w1T, bb1,
        hid, nullptr, nullptr, CH, 3072, 768, 6);
    gemm_s<3><<<dim3(CH / 128, 6), 256, 0, stream>>>(hid, w2T, bb2,
        (float*)d_out + ro * 768, res2 + ro * 768, CH, 768, 3072, 3);
  }
}

// Round 19
// 486.963 us; speedup vs baseline: 1.0535x; 1.0535x over previous
//
#include <hip/hip_runtime.h>
#include <hip/hip_bf16.h>
#include <math.h>

#define D_MODEL 768
#define T_SEQ   1024
#define B_BATCH 16
#define MLP_DIM 3072
#define M_ROWS  (B_BATCH * T_SEQ)   // 16384

typedef __attribute__((ext_vector_type(8))) __bf16          bf16x8;
typedef __attribute__((ext_vector_type(4))) __bf16          bf16x4;
typedef __attribute__((ext_vector_type(4))) float           f32x4;

__device__ __forceinline__ float bf2f(unsigned short u) {
  union { unsigned int u; float f; } w; w.u = ((unsigned int)u) << 16; return w.f;
}
__device__ __forceinline__ unsigned short f2bf(float f) {
  union { float f; unsigned int u; } w; w.f = f;
  unsigned int r = (w.u + 0x7fffu + ((w.u >> 16) & 1u)) >> 16;
  return (unsigned short)r;
}
// fast GELU: tanh-form, x / (1 + 2^(x*(a + b x^2))), |err| <= ~3e-3 vs erf
__device__ __forceinline__ float gelu_f(float x) {
  const float a2 = -2.302283f, b2 = -0.102947f;
  return x / (1.0f + exp2f(x * fmaf(b2, x * x, a2)));
}
// async global->LDS, 16B per lane; LDS dest = wave-uniform base + lane*16
__device__ __forceinline__ void gload16(const void* g, void* l) {
  __builtin_amdgcn_global_load_lds(
      (const __attribute__((address_space(1))) unsigned int*)g,
      (__attribute__((address_space(3))) unsigned int*)l, 16, 0, 0);
}

// ------- weight transpose+convert: dst[N=C][K=R] bf16 = src[R][C] f32 ------
__global__ void wtr_k(const float* __restrict__ src,
                      unsigned short* __restrict__ dst, int R, int C) {
  __shared__ float t[32][33];
  const int c0 = blockIdx.x * 32, r0 = blockIdx.y * 32;
  const int tx = threadIdx.x, ty = threadIdx.y;
  #pragma unroll
  for (int j = 0; j < 32; j += 8)
    t[ty + j][tx] = src[(size_t)(r0 + ty + j) * C + (c0 + tx)];
  __syncthreads();
  #pragma unroll
  for (int j = 0; j < 32; j += 8)
    dst[(size_t)(c0 + ty + j) * R + (r0 + tx)] = f2bf(t[tx][ty + j]);
}

// ------- concat 3 bias vectors of 768 f32 --------------------------------
__global__ void bcat_k(const float* __restrict__ a, const float* __restrict__ b,
                       const float* __restrict__ c, float* __restrict__ o) {
  const int i = blockIdx.x * 256 + threadIdx.x;
  if (i < 768) { o[i] = a[i]; o[i + 768] = b[i]; o[i + 1536] = c[i]; }
}

// ---------- fused LayerNorm (stats + apply), one block per row -------------
template<int SRC_F32>
__global__ __launch_bounds__(256) void ln_k(const void* __restrict__ src,
    const float* __restrict__ g, const float* __restrict__ b,
    unsigned short* __restrict__ out) {
  const int row = blockIdx.x, tid = threadIdx.x;
  const size_t base = (size_t)row * D_MODEL;
  float v[3];
  #pragma unroll
  for (int i = 0; i < 3; ++i) {
    const int c = tid + (i << 8);
    v[i] = SRC_F32 ? ((const float*)src)[base + c]
                   : bf2f(((const unsigned short*)src)[base + c]);
  }
  float s  = v[0] + v[1] + v[2];
  float sq = v[0]*v[0] + v[1]*v[1] + v[2]*v[2];
  #pragma unroll
  for (int m = 32; m; m >>= 1) { s += __shfl_xor(s, m); sq += __shfl_xor(sq, m); }
  __shared__ float ps[4], pq[4];
  if ((tid & 63) == 0) { ps[tid >> 6] = s; pq[tid >> 6] = sq; }
  __syncthreads();
  s  = ps[0] + ps[1] + ps[2] + ps[3];
  sq = pq[0] + pq[1] + pq[2] + pq[3];
  const float mu  = s * (1.0f / 768.0f);
  const float var = sq * (1.0f / 768.0f) - mu * mu;
  const float inv = rsqrtf(var + 1e-5f);
  #pragma unroll
  for (int i = 0; i < 3; ++i) {
    const int c = tid + (i << 8);
    out[base + c] = f2bf((v[i] - mu) * inv * g[c] + b[c]);
  }
}

// ---- GEMM (large): 256x256 tile, BK=64, 8 waves, dbuf 128KB, 4-phase ------
// (round-13/17 structure, best measured). Counted vmcnt(2) once per tile.
// EP 1: gelu->bf16 | EP 5: fused QKV split store (outv=q, residv=k, aux=v^T)
template<int EP>
__global__ __launch_bounds__(512) void gemm_k(
    const unsigned short* __restrict__ Au, const unsigned short* __restrict__ Btu,
    const float* __restrict__ bias, void* __restrict__ outv,
    const void* __restrict__ residv, void* __restrict__ aux,
    int M, int N, int K, int cgrp) {
  __shared__ __align__(16) __bf16 SMEM[2 * 32768];          // 128 KB
  const __bf16* A  = (const __bf16*)Au;
  const __bf16* Bt = (const __bf16*)Btu;
  const int tid = threadIdx.x;
  const int lane = tid & 63, w = tid >> 6;      // 8 waves
  const int wr = w >> 2, wc = w & 3;            // 2 x 4 wave grid
  const int lr = lane & 15, lg = lane >> 4;
  const int gx = gridDim.x;
  const int bid = blockIdx.y * gx + blockIdx.x;
  const int xcd = bid & 7, idx = bid >> 3;
  const int rpx = gx >> 3;
  const int gsz = rpx * cgrp;
  const int grp = idx / gsz, rem = idx - grp * gsz;
  const int rb = rem / cgrp, cc2 = rem - rb * cgrp + grp * cgrp;
  const int brow = (xcd * rpx + rb) * 256;
  const int bcol = cc2 * 256;

  f32x4 acc[8][4];
  #pragma unroll
  for (int m = 0; m < 8; ++m)
    #pragma unroll
    for (int n = 0; n < 4; ++n) acc[m][n] = (f32x4){0.f, 0.f, 0.f, 0.f};

  const int rrs = lane >> 2;
  const int ccs = (lane & 3) << 3;
  const int csw = ccs ^ ((((lane >> 3) & 3)) << 3);
  const __bf16* sA[4]; const __bf16* sB[4]; int dA[4], dB[4];
  #pragma unroll
  for (int g = 0; g < 4; ++g) {
    const int s = g * 8 + w;
    const int rsrc = (s >> 1) * 16 + rrs;
    const int csrc = (s & 1) * 32 + csw;
    sA[g] = A  + (size_t)(brow + rsrc) * K + csrc;
    sB[g] = Bt + (size_t)(bcol + rsrc) * K + csrc;
    dA[g] = s * 512;
    dB[g] = 16384 + s * 512;
  }

#define STAGE2_(nbb_, k0_, g_) do {                         \
    gload16(sA[g_] + (k0_), &SMEM[(nbb_) + dA[g_]]);        \
    gload16(sB[g_] + (k0_), &SMEM[(nbb_) + dB[g_]]);        \
  } while (0)

  const int rbase = lr * 32 + ((lg << 3) ^ (((lr >> 1) & 3) << 3));

  #pragma unroll
  for (int g = 0; g < 4; ++g) STAGE2_(0, 0, g);

  int cur = 0;
  for (int k0 = 0; k0 < K; k0 += 64, cur ^= 1) {
    const int bb  = cur * 32768;
    const int nbb = (cur ^ 1) * 32768;
    const bool pf = (k0 + 64 < K);
    bf16x8 af0[4][2], af1[4][2], bfr[4][2];
    // P1
    if (pf) {
      STAGE2_(nbb, k0 + 64, 0);
      asm volatile("s_waitcnt vmcnt(2)" ::: "memory");
    } else {
      asm volatile("s_waitcnt vmcnt(0)" ::: "memory");
    }
    __builtin_amdgcn_s_barrier();
    __builtin_amdgcn_sched_barrier(0);
    #pragma unroll
    for (int ml = 0; ml < 4; ++ml)
      #pragma unroll
      for (int kk = 0; kk < 2; ++kk)
        af0[ml][kk] = *(const bf16x8*)(&SMEM[bb + ((wr*8 + ml)*2 + kk)*512 + rbase]);
    #pragma unroll
    for (int n = 0; n < 2; ++n)
      #pragma unroll
      for (int kk = 0; kk < 2; ++kk)
        bfr[n][kk] = *(const bf16x8*)(&SMEM[bb + 16384 + ((wc*4 + n)*2 + kk)*512 + rbase]);
    asm volatile("s_waitcnt lgkmcnt(0)" ::: "memory");
    __builtin_amdgcn_sched_barrier(0);
    __builtin_amdgcn_s_setprio(1);
    #pragma unroll
    for (int ml = 0; ml < 4; ++ml)
      #pragma unroll
      for (int n = 0; n < 2; ++n) {
        acc[ml][n] = __builtin_amdgcn_mfma_f32_16x16x32_bf16(af0[ml][0], bfr[n][0], acc[ml][n], 0, 0, 0);
        acc[ml][n] = __builtin_amdgcn_mfma_f32_16x16x32_bf16(af0[ml][1], bfr[n][1], acc[ml][n], 0, 0, 0);
      }
    __builtin_amdgcn_s_setprio(0);
    __builtin_amdgcn_s_barrier();
    // P2
    #pragma unroll
    for (int n = 2; n < 4; ++n)
      #pragma unroll
      for (int kk = 0; kk < 2; ++kk)
        bfr[n][kk] = *(const bf16x8*)(&SMEM[bb + 16384 + ((wc*4 + n)*2 + kk)*512 + rbase]);
    if (pf) STAGE2_(nbb, k0 + 64, 1);
    asm volatile("s_waitcnt lgkmcnt(0)" ::: "memory");
    __builtin_amdgcn_sched_barrier(0);
    __builtin_amdgcn_s_setprio(1);
    #pragma unroll
    for (int ml = 0; ml < 4; ++ml)
      #pragma unroll
      for (int n = 2; n < 4; ++n) {
        acc[ml][n] = __builtin_amdgcn_mfma_f32_16x16x32_bf16(af0[ml][0], bfr[n][0], acc[ml][n], 0, 0, 0);
        acc[ml][n] = __builtin_amdgcn_mfma_f32_16x16x32_bf16(af0[ml][1], bfr[n][1], acc[ml][n], 0, 0, 0);
      }
    __builtin_amdgcn_s_setprio(0);
    __builtin_amdgcn_s_barrier();
    // P3
    #pragma unroll
    for (int ml = 0; ml < 4; ++ml)
      #pragma unroll
      for (int kk = 0; kk < 2; ++kk)
        af1[ml][kk] = *(const bf16x8*)(&SMEM[bb + ((wr*8 + 4 + ml)*2 + kk)*512 + rbase]);
    if (pf) STAGE2_(nbb, k0 + 64, 2);
    asm volatile("s_waitcnt lgkmcnt(0)" ::: "memory");
    __builtin_amdgcn_sched_barrier(0);
    __builtin_amdgcn_s_setprio(1);
    #pragma unroll
    for (int ml = 0; ml < 4; ++ml)
      #pragma unroll
      for (int n = 0; n < 2; ++n) {
        acc[4+ml][n] = __builtin_amdgcn_mfma_f32_16x16x32_bf16(af1[ml][0], bfr[n][0], acc[4+ml][n], 0, 0, 0);
        acc[4+ml][n] = __builtin_amdgcn_mfma_f32_16x16x32_bf16(af1[ml][1], bfr[n][1], acc[4+ml][n], 0, 0, 0);
      }
    __builtin_amdgcn_s_setprio(0);
    __builtin_amdgcn_s_barrier();
    // P4
    if (pf) STAGE2_(nbb, k0 + 64, 3);
    __builtin_amdgcn_s_setprio(1);
    #pragma unroll
    for (int ml = 0; ml < 4; ++ml)
      #pragma unroll
      for (int n = 2; n < 4; ++n) {
        acc[4+ml][n] = __builtin_amdgcn_mfma_f32_16x16x32_bf16(af1[ml][0], bfr[n][0], acc[4+ml][n], 0, 0, 0);
        acc[4+ml][n] = __builtin_amdgcn_mfma_f32_16x16x32_bf16(af1[ml][1], bfr[n][1], acc[4+ml][n], 0, 0, 0);
      }
    __builtin_amdgcn_s_setprio(0);
    __builtin_amdgcn_s_barrier();
  }
#undef STAGE2_

  const int seg = (EP == 5) ? (bcol / 768) : 0;
  unsigned short* qkvp = nullptr;
  if (EP == 5)
    qkvp = (seg == 0) ? (unsigned short*)outv
         : (seg == 1) ? (unsigned short*)residv : (unsigned short*)aux;

  if (EP == 5 && seg == 2) {
    #pragma unroll
    for (int n = 0; n < 4; ++n) {
      const int col = bcol + wc*64 + n*16 + lr;
      const float bv = bias[col];
      const int colLv = col - 1536;
      #pragma unroll
      for (int m = 0; m < 8; ++m) {
        const int row0 = brow + wr*128 + m*16 + lg*4;
        #pragma unroll
        for (int r2 = 0; r2 < 4; ++r2) {
          const int gr = row0 + r2;
          qkvp[(((size_t)(gr >> 10) * D_MODEL + colLv) << 10) + (gr & 1023)] =
              f2bf(acc[m][n][r2] + bv);
        }
      }
    }
  } else {
    float* Ep = (float*)SMEM + w * 1280;
    #pragma unroll
    for (int m = 0; m < 8; ++m) {
      #pragma unroll
      for (int n = 0; n < 4; ++n) {
        const int col = bcol + wc*64 + n*16 + lr;
        const float bv = bias[col];
        f32x4 st;
        #pragma unroll
        for (int r2 = 0; r2 < 4; ++r2) {
          float v = acc[m][n][r2] + bv;
          if (EP == 1) v = gelu_f(v);
          st[r2] = v;
        }
        *(f32x4*)(Ep + (n*16 + lr) * 20 + lg*4) = st;
      }
      #pragma unroll
      for (int i2 = 0; i2 < 2; ++i2) {
        const int rowL = i2*8 + (lane >> 3);
        const int colL = (lane & 7) * 8;
        const int grow = brow + wr*128 + m*16 + rowL;
        const int gcol = bcol + wc*64 + colL;
        float v[8];
        #pragma unroll
        for (int j = 0; j < 8; ++j) v[j] = Ep[(colL + j) * 20 + rowL];
        const size_t o = (size_t)grow * N + gcol;
        if (EP == 5) {
          bf16x8 ov;
          #pragma unroll
          for (int j = 0; j < 8; ++j) ov[j] = (__bf16)v[j];
          *(bf16x8*)((__bf16*)qkvp + (size_t)grow * 768 + (gcol - seg * 768)) = ov;
        } else {               // EP 0 / 1
          bf16x8 ov;
          #pragma unroll
          for (int j = 0; j < 8; ++j) ov[j] = (__bf16)v[j];
          *(bf16x8*)((__bf16*)outv + o) = ov;
        }
      }
    }
  }
}

// ---- GEMM (mid, N=768): 128x128 tile, BK=64, 4 waves, 64KB dbuf, 2-phase --
// 32 MFMA/iter, counted vmcnt(4) (8 gloads/tile/wave, 4 per phase).
// EP 2: +resid(f32) -> bf16 | EP 3: gelu + resid(bf16) -> f32 (final output)
template<int EP>
__global__ __launch_bounds__(256) void gemm_m(
    const unsigned short* __restrict__ Au, const unsigned short* __restrict__ Btu,
    const float* __restrict__ bias, void* __restrict__ outv,
    const void* __restrict__ residv, int M, int N, int K, int cgrp) {
  __shared__ __align__(16) __bf16 SMEM[2 * 16384];          // 64 KB
  const __bf16* A  = (const __bf16*)Au;
  const __bf16* Bt = (const __bf16*)Btu;
  const int tid = threadIdx.x;
  const int lane = tid & 63, w = tid >> 6;      // 4 waves
  const int wr = w >> 1, wc = w & 1;            // 2 x 2 wave grid
  const int lr = lane & 15, lg = lane >> 4;
  const int gx = gridDim.x;
  const int bid = blockIdx.y * gx + blockIdx.x;
  const int xcd = bid & 7, idx = bid >> 3;
  const int rpx = gx >> 3;
  const int gsz = rpx * cgrp;
  const int grp = idx / gsz, rem = idx - grp * gsz;
  const int rb = rem / cgrp, cc2 = rem - rb * cgrp + grp * cgrp;
  const int brow = (xcd * rpx + rb) * 128;
  const int bcol = cc2 * 128;

  f32x4 acc[4][4];
  #pragma unroll
  for (int m = 0; m < 4; ++m)
    #pragma unroll
    for (int n = 0; n < 4; ++n) acc[m][n] = (f32x4){0.f, 0.f, 0.f, 0.f};

  // staging: wave w + slot g covers subtile s = g*4 + w (A and B each)
  const int rrs = lane >> 2;
  const int ccs = (lane & 3) << 3;
  const int csw = ccs ^ ((((lane >> 3) & 3)) << 3);   // inverse swizzle
  const __bf16* sA[4]; const __bf16* sB[4]; int dA[4], dB[4];
  #pragma unroll
  for (int g = 0; g < 4; ++g) {
    const int s = g * 4 + w;                    // 0..15
    const int rsrc = (s >> 1) * 16 + rrs;
    const int csrc = (s & 1) * 32 + csw;
    sA[g] = A  + (size_t)(brow + rsrc) * K + csrc;
    sB[g] = Bt + (size_t)(bcol + rsrc) * K + csrc;
    dA[g] = s * 512;
    dB[g] = 8192 + s * 512;
  }

#define STAGEM_(nbb_, k0_, g_) do {                         \
    gload16(sA[g_] + (k0_), &SMEM[(nbb_) + dA[g_]]);        \
    gload16(sB[g_] + (k0_), &SMEM[(nbb_) + dB[g_]]);        \
  } while (0)

  const int rbase = lr * 32 + ((lg << 3) ^ (((lr >> 1) & 3) << 3));

  #pragma unroll
  for (int g = 0; g < 4; ++g) STAGEM_(0, 0, g);   // prologue: tile 0 (8 gloads)

  int cur = 0;
  for (int k0 = 0; k0 < K; k0 += 64, cur ^= 1) {
    const int bb  = cur * 16384;
    const int nbb = (cur ^ 1) * 16384;
    const bool pf = (k0 + 64 < K);
    bf16x8 af[4][2], bfr[4][2];
    // P1: stage g0,g1 of next tile; drain current tile (vmcnt 4)
    if (pf) {
      STAGEM_(nbb, k0 + 64, 0);
      STAGEM_(nbb, k0 + 64, 1);
      asm volatile("s_waitcnt vmcnt(4)" ::: "memory");
    } else {
      asm volatile("s_waitcnt vmcnt(0)" ::: "memory");
    }
    __builtin_amdgcn_s_barrier();
    __builtin_amdgcn_sched_barrier(0);
    #pragma unroll
    for (int ml = 0; ml < 4; ++ml)
      #pragma unroll
      for (int kk = 0; kk < 2; ++kk)
        af[ml][kk] = *(const bf16x8*)(&SMEM[bb + ((wr*4 + ml)*2 + kk)*512 + rbase]);
    #pragma unroll
    for (int n = 0; n < 2; ++n)
      #pragma unroll
      for (int kk = 0; kk < 2; ++kk)
        bfr[n][kk] = *(const bf16x8*)(&SMEM[bb + 8192 + ((wc*4 + n)*2 + kk)*512 + rbase]);
    asm volatile("s_waitcnt lgkmcnt(0)" ::: "memory");
    __builtin_amdgcn_sched_barrier(0);
    __builtin_amdgcn_s_setprio(1);
    #pragma unroll
    for (int ml = 0; ml < 4; ++ml)
      #pragma unroll
      for (int n = 0; n < 2; ++n) {
        acc[ml][n] = __builtin_amdgcn_mfma_f32_16x16x32_bf16(af[ml][0], bfr[n][0], acc[ml][n], 0, 0, 0);
        acc[ml][n] = __builtin_amdgcn_mfma_f32_16x16x32_bf16(af[ml][1], bfr[n][1], acc[ml][n], 0, 0, 0);
      }
    __builtin_amdgcn_s_setprio(0);
    __builtin_amdgcn_s_barrier();
    // P2: read bfr n=2,3; stage g2,g3
    #pragma unroll
    for (int n = 2; n < 4; ++n)
      #pragma unroll
      for (int kk = 0; kk < 2; ++kk)
        bfr[n][kk] = *(const bf16x8*)(&SMEM[bb + 8192 + ((wc*4 + n)*2 + kk)*512 + rbase]);
    if (pf) {
      STAGEM_(nbb, k0 + 64, 2);
      STAGEM_(nbb, k0 + 64, 3);
    }
    asm volatile("s_waitcnt lgkmcnt(0)" ::: "memory");
    __builtin_amdgcn_sched_barrier(0);
    __builtin_amdgcn_s_setprio(1);
    #pragma unroll
    for (int ml = 0; ml < 4; ++ml)
      #pragma unroll
      for (int n = 2; n < 4; ++n) {
        acc[ml][n] = __builtin_amdgcn_mfma_f32_16x16x32_bf16(af[ml][0], bfr[n][0], acc[ml][n], 0, 0, 0);
        acc[ml][n] = __builtin_amdgcn_mfma_f32_16x16x32_bf16(af[ml][1], bfr[n][1], acc[ml][n], 0, 0, 0);
      }
    __builtin_amdgcn_s_setprio(0);
    __builtin_amdgcn_s_barrier();
  }
#undef STAGEM_

  // coalesced bounce epilogue: per-wave f32 tile [64 col][20 row]
  float* Ep = (float*)SMEM + w * 1280;
  #pragma unroll
  for (int p = 0; p < 4; ++p) {
    #pragma unroll
    for (int n = 0; n < 4; ++n) {
      const int col = bcol + wc*64 + n*16 + lr;
      const float bv = bias[col];
      f32x4 st;
      #pragma unroll
      for (int r2 = 0; r2 < 4; ++r2) {
        float v = acc[p][n][r2] + bv;
        if (EP == 3) v = gelu_f(v);
        st[r2] = v;
      }
      *(f32x4*)(Ep + (n*16 + lr) * 20 + lg*4) = st;
    }
    #pragma unroll
    for (int i2 = 0; i2 < 2; ++i2) {
      const int rowL = i2*8 + (lane >> 3);
      const int colL = (lane & 7) * 8;
      const int grow = brow + wr*64 + p*16 + rowL;
      const int gcol = bcol + wc*64 + colL;
      float v[8];
      #pragma unroll
      for (int j = 0; j < 8; ++j) v[j] = Ep[(colL + j) * 20 + rowL];
      const size_t o = (size_t)grow * N + gcol;
      if (EP == 3) {                 // gelu applied; + resid(bf16) -> f32
        const bf16x8 rv = *(const bf16x8*)((const __bf16*)residv + o);
        float* op = (float*)outv + o;
        float4 o0, o1;
        o0.x = v[0] + (float)rv[0]; o0.y = v[1] + (float)rv[1];
        o0.z = v[2] + (float)rv[2]; o0.w = v[3] + (float)rv[3];
        o1.x = v[4] + (float)rv[4]; o1.y = v[5] + (float)rv[5];
        o1.z = v[6] + (float)rv[6]; o1.w = v[7] + (float)rv[7];
        *(float4*)op = o0; *(float4*)(op + 4) = o1;
      } else {                       // EP 2: + resid(f32) -> bf16
        const float* rp = (const float*)residv + o;
        const float4 r0 = *(const float4*)rp, r1 = *(const float4*)(rp + 4);
        bf16x8 ov;
        ov[0] = (__bf16)(v[0] + r0.x); ov[1] = (__bf16)(v[1] + r0.y);
        ov[2] = (__bf16)(v[2] + r0.z); ov[3] = (__bf16)(v[3] + r0.w);
        ov[4] = (__bf16)(v[4] + r1.x); ov[5] = (__bf16)(v[5] + r1.y);
        ov[6] = (__bf16)(v[6] + r1.z); ov[7] = (__bf16)(v[7] + r1.w);
        *(bf16x8*)((__bf16*)outv + o) = ov;
      }
    }
  }
}

// ---------------- flash attention: 768 blocks, XCD-sequential bh -----------
__global__ __launch_bounds__(512) void attn_k(
    const unsigned short* qu, const unsigned short* __restrict__ ku,
    const unsigned short* __restrict__ vtu, unsigned short* attn) {
  __shared__ __align__(16) __bf16 Kl[64][72];
  __shared__ __align__(16) __bf16 Vl[64][72];
  __shared__ __align__(16) __bf16 Pl[8][16][72];
  const __bf16* qg  = (const __bf16*)qu;
  const __bf16* kg  = (const __bf16*)ku;
  const __bf16* vtg = (const __bf16*)vtu;
  const int bid = blockIdx.x;
  const int xcd = bid & 7, idx = bid >> 3;
  const int bh = xcd * 24 + (idx >> 2);
  const int b = bh / 12, h = bh % 12;
  const int q0 = (idx & 3) * 256;
  const int tid = threadIdx.x, lane = tid & 63, w = tid >> 6;
  const int lr = lane & 15, lg = lane >> 4;
  const float scale = 0.03608439182435161f; // 1/sqrt(768)

  bf16x8 qa[2][2];
  #pragma unroll
  for (int g = 0; g < 2; ++g) {
    const int qrow = b * T_SEQ + q0 + w * 32 + g * 16 + lr;
    const __bf16* qp = qg + (size_t)qrow * D_MODEL + h * 64 + lg * 8;
    qa[g][0] = *(const bf16x8*)(qp);
    qa[g][1] = *(const bf16x8*)(qp + 32);
  }

  const __bf16* kb = kg  + (size_t)b * T_SEQ * D_MODEL + h * 64;
  const __bf16* vb = vtg + ((size_t)b * D_MODEL + h * 64) * T_SEQ;

  f32x4 o[2][4];
  float m_run[2] = {-1e30f, -1e30f}, l_run[2] = {0.f, 0.f};
  #pragma unroll
  for (int g = 0; g < 2; ++g)
    #pragma unroll
    for (int m = 0; m < 4; ++m) o[g][m] = (f32x4){0.f, 0.f, 0.f, 0.f};

  for (int kv0 = 0; kv0 < T_SEQ; kv0 += 64) {
    __syncthreads();
    {
      const int r = tid >> 3, c = (tid & 7) << 3;
      *(bf16x8*)(&Kl[r][c]) = *(const bf16x8*)(kb + (size_t)(kv0 + r) * D_MODEL + c);
      *(bf16x8*)(&Vl[r][c]) = *(const bf16x8*)(vb + (size_t)r * T_SEQ + kv0 + c);
    }
    __syncthreads();

    #pragma unroll
    for (int g = 0; g < 2; ++g) {
      f32x4 s[4];
      __builtin_amdgcn_s_setprio(1);
      #pragma unroll
      for (int m = 0; m < 4; ++m) {
        s[m] = (f32x4){0.f, 0.f, 0.f, 0.f};
        const bf16x8 kf0 = *(const bf16x8*)(&Kl[m*16 + lr][lg*8]);
        const bf16x8 kf1 = *(const bf16x8*)(&Kl[m*16 + lr][32 + lg*8]);
        s[m] = __builtin_amdgcn_mfma_f32_16x16x32_bf16(kf0, qa[g][0], s[m], 0, 0, 0);
        s[m] = __builtin_amdgcn_mfma_f32_16x16x32_bf16(kf1, qa[g][1], s[m], 0, 0, 0);
      }
      __builtin_amdgcn_s_setprio(0);
      float sv[4][4], tm = -1e30f;
      #pragma unroll
      for (int m = 0; m < 4; ++m)
        #pragma unroll
        for (int r = 0; r < 4; ++r) {
          sv[m][r] = s[m][r] * scale;
          tm = fmaxf(tm, sv[m][r]);
        }
      tm = fmaxf(tm, __shfl_xor(tm, 16));
      tm = fmaxf(tm, __shfl_xor(tm, 32));
      const float mn = fmaxf(m_run[g], tm);
      const float sc = __expf(m_run[g] - mn);
      float ts = 0.f;
      bf16x4 pk[4];
      #pragma unroll
      for (int m = 0; m < 4; ++m)
        #pragma unroll
        for (int r = 0; r < 4; ++r) {
          const float pp = __expf(sv[m][r] - mn);
          ts += pp;
          pk[m][r] = (__bf16)pp;
        }
      ts += __shfl_xor(ts, 16);
      ts += __shfl_xor(ts, 32);
      l_run[g] = l_run[g] * sc + ts;
      m_run[g] = mn;
      #pragma unroll
      for (int m = 0; m < 4; ++m)
        #pragma unroll
        for (int r = 0; r < 4; ++r) o[g][m][r] *= sc;
      #pragma unroll
      for (int m = 0; m < 4; ++m)
        *(bf16x4*)(&Pl[w][lr][16*m + 4*lg]) = pk[m];
      const bf16x8 pf0 = *(const bf16x8*)(&Pl[w][lr][lg*8]);
      const bf16x8 pf1 = *(const bf16x8*)(&Pl[w][lr][32 + lg*8]);
      __builtin_amdgcn_s_setprio(1);
      #pragma unroll
      for (int m = 0; m < 4; ++m) {
        const bf16x8 vf0 = *(const bf16x8*)(&Vl[m*16 + lr][lg*8]);
        const bf16x8 vf1 = *(const bf16x8*)(&Vl[m*16 + lr][32 + lg*8]);
        o[g][m] = __builtin_amdgcn_mfma_f32_16x16x32_bf16(vf0, pf0, o[g][m], 0, 0, 0);
        o[g][m] = __builtin_amdgcn_mfma_f32_16x16x32_bf16(vf1, pf1, o[g][m], 0, 0, 0);
      }
      __builtin_amdgcn_s_setprio(0);
    }
  }

  #pragma unroll
  for (int g = 0; g < 2; ++g) {
    const float inv = 1.0f / l_run[g];
    const int qrow = b * T_SEQ + q0 + w * 32 + g * 16 + lr;
    unsigned short* op = attn + (size_t)qrow * D_MODEL + h * 64;
    #pragma unroll
    for (int m = 0; m < 4; ++m) {
      bf16x4 ov;
      #pragma unroll
      for (int r = 0; r < 4; ++r) ov[r] = (__bf16)(o[g][m][r] * inv);
      *(bf16x4*)(op + 16*m + 4*lg) = ov;
    }
  }
}

// ---------------------------------------------------------------------------
extern "C" void kernel_launch(void* const* d_in, const int* in_sizes, int n_in,
                              void* d_out, int out_size, void* d_ws, size_t ws_size,
                              hipStream_t stream) {
  const float* x   = (const float*)d_in[0];
  const float* Wq  = (const float*)d_in[1];
  const float* bq  = (const float*)d_in[2];
  const float* Wk  = (const float*)d_in[3];
  const float* bk  = (const float*)d_in[4];
  const float* Wv  = (const float*)d_in[5];
  const float* bv  = (const float*)d_in[6];
  const float* Wo  = (const float*)d_in[7];
  const float* bo  = (const float*)d_in[8];
  const float* g1  = (const float*)d_in[9];
  const float* bt1 = (const float*)d_in[10];
  const float* g2  = (const float*)d_in[11];
  const float* bt2 = (const float*)d_in[12];
  const float* W1  = (const float*)d_in[13];
  const float* bb1 = (const float*)d_in[14];
  const float* W2  = (const float*)d_in[15];
  const float* bb2 = (const float*)d_in[16];

  const size_t SZ = (size_t)M_ROWS * D_MODEL * 2;   // 25,165,824
  char* wp = (char*)d_ws;
  unsigned short* wqkvT = (unsigned short*)wp; wp += (size_t)2304 * 768 * 2;
  unsigned short* woT   = (unsigned short*)wp; wp += (size_t)768 * 768 * 2;
  unsigned short* w1T   = (unsigned short*)wp; wp += (size_t)768 * 3072 * 2;
  unsigned short* w2T   = (unsigned short*)wp; wp += (size_t)768 * 3072 * 2;
  float*          bqkv  = (float*)wp;          wp += ((size_t)2304 * 4 + 255) & ~(size_t)255;
  unsigned short* kbuf  = (unsigned short*)wp; wp += SZ;   // k -> res2
  unsigned short* vtb   = (unsigned short*)wp;             // vT -> hid
  unsigned short* res2  = kbuf;
  unsigned short* hid   = vtb;
  const size_t avail = ws_size - (size_t)(wp - (char*)d_ws);
  const int nch = (avail >= (size_t)M_ROWS * MLP_DIM * 2) ? 1
                : (avail >= (size_t)(M_ROWS / 2) * MLP_DIM * 2) ? 2 : 4;

  unsigned short* qd = (unsigned short*)d_out;             // bf16 lo half
  unsigned short* h1 = qd + (size_t)M_ROWS * D_MODEL;      // bf16 hi half
  unsigned short* h2 = h1;

  const dim3 tb(32, 8, 1);
  wtr_k<<<dim3(24, 24), tb, 0, stream>>>(Wq, wqkvT, 768, 768);
  wtr_k<<<dim3(24, 24), tb, 0, stream>>>(Wk, wqkvT + (size_t)768 * 768, 768, 768);
  wtr_k<<<dim3(24, 24), tb, 0, stream>>>(Wv, wqkvT + (size_t)1536 * 768, 768, 768);
  wtr_k<<<dim3(24, 24), tb, 0, stream>>>(Wo, woT, 768, 768);
  wtr_k<<<dim3(96, 24), tb, 0, stream>>>(W1, w1T, 768, 3072);
  wtr_k<<<dim3(24, 96), tb, 0, stream>>>(W2, w2T, 3072, 768);
  bcat_k<<<3, 256, 0, stream>>>(bq, bk, bv, bqkv);

  ln_k<1><<<M_ROWS, 256, 0, stream>>>(x, g1, bt1, h1);

  gemm_k<5><<<dim3(64, 9), 512, 0, stream>>>(h1, wqkvT, bqkv, qd, kbuf, vtb,
                                             M_ROWS, 2304, 768, 9);

  attn_k<<<dim3(768), 512, 0, stream>>>(qd, kbuf, vtb, qd);

  gemm_m<2><<<dim3(128, 6), 256, 0, stream>>>(qd, woT, bo, res2, x,
                                              M_ROWS, 768, 768, 3);

  ln_k<0><<<M_ROWS, 256, 0, stream>>>(res2, g2, bt2, h2);

  const int CH = M_ROWS / nch;
  for (int c = 0; c < nch; ++c) {
    const size_t ro = (size_t)c * CH;
    gemm_k<1><<<dim3(CH / 256, 12), 512, 0, stream>>>(h2 + ro * 768, w1T, bb1,
        hid, nullptr, nullptr, CH, 3072, 768, 6);
    gemm_m<3><<<dim3(CH / 128, 6), 256, 0, stream>>>(hid, w2T, bb2,
        (float*)d_out + ro * 768, res2 + ro * 768, CH, 768, 3072, 3);
  }
}

// Round 20
// 486.769 us; speedup vs baseline: 1.0539x; 1.0004x over previous
//
#include <hip/hip_runtime.h>
#include <hip/hip_bf16.h>
#include <math.h>

#define D_MODEL 768
#define T_SEQ   1024
#define B_BATCH 16
#define MLP_DIM 3072
#define M_ROWS  (B_BATCH * T_SEQ)   // 16384

typedef __attribute__((ext_vector_type(8))) __bf16          bf16x8;
typedef __attribute__((ext_vector_type(4))) __bf16          bf16x4;
typedef __attribute__((ext_vector_type(4))) float           f32x4;

__device__ __forceinline__ float bf2f(unsigned short u) {
  union { unsigned int u; float f; } w; w.u = ((unsigned int)u) << 16; return w.f;
}
__device__ __forceinline__ unsigned short f2bf(float f) {
  union { float f; unsigned int u; } w; w.f = f;
  unsigned int r = (w.u + 0x7fffu + ((w.u >> 16) & 1u)) >> 16;
  return (unsigned short)r;
}
// fast GELU: tanh-form, x / (1 + 2^(x*(a + b x^2))), |err| <= ~3e-3 vs erf
__device__ __forceinline__ float gelu_f(float x) {
  const float a2 = -2.302283f, b2 = -0.102947f;
  return x / (1.0f + exp2f(x * fmaf(b2, x * x, a2)));
}
// async global->LDS, 16B per lane; LDS dest = wave-uniform base + lane*16
__device__ __forceinline__ void gload16(const void* g, void* l) {
  __builtin_amdgcn_global_load_lds(
      (const __attribute__((address_space(1))) unsigned int*)g,
      (__attribute__((address_space(3))) unsigned int*)l, 16, 0, 0);
}

// ------- weight transpose+convert: dst[N=C][K=R] bf16 = src[R][C] f32 ------
__global__ void wtr_k(const float* __restrict__ src,
                      unsigned short* __restrict__ dst, int R, int C) {
  __shared__ float t[32][33];
  const int c0 = blockIdx.x * 32, r0 = blockIdx.y * 32;
  const int tx = threadIdx.x, ty = threadIdx.y;
  #pragma unroll
  for (int j = 0; j < 32; j += 8)
    t[ty + j][tx] = src[(size_t)(r0 + ty + j) * C + (c0 + tx)];
  __syncthreads();
  #pragma unroll
  for (int j = 0; j < 32; j += 8)
    dst[(size_t)(c0 + ty + j) * R + (r0 + tx)] = f2bf(t[tx][ty + j]);
}

// ------- concat 3 bias vectors of 768 f32 --------------------------------
__global__ void bcat_k(const float* __restrict__ a, const float* __restrict__ b,
                       const float* __restrict__ c, float* __restrict__ o) {
  const int i = blockIdx.x * 256 + threadIdx.x;
  if (i < 768) { o[i] = a[i]; o[i + 768] = b[i]; o[i + 1536] = c[i]; }
}

// ---------- fused LayerNorm (stats + apply), one block per row -------------
template<int SRC_F32>
__global__ __launch_bounds__(256) void ln_k(const void* __restrict__ src,
    const float* __restrict__ g, const float* __restrict__ b,
    unsigned short* __restrict__ out) {
  const int row = blockIdx.x, tid = threadIdx.x;
  const size_t base = (size_t)row * D_MODEL;
  float v[3];
  #pragma unroll
  for (int i = 0; i < 3; ++i) {
    const int c = tid + (i << 8);
    v[i] = SRC_F32 ? ((const float*)src)[base + c]
                   : bf2f(((const unsigned short*)src)[base + c]);
  }
  float s  = v[0] + v[1] + v[2];
  float sq = v[0]*v[0] + v[1]*v[1] + v[2]*v[2];
  #pragma unroll
  for (int m = 32; m; m >>= 1) { s += __shfl_xor(s, m); sq += __shfl_xor(sq, m); }
  __shared__ float ps[4], pq[4];
  if ((tid & 63) == 0) { ps[tid >> 6] = s; pq[tid >> 6] = sq; }
  __syncthreads();
  s  = ps[0] + ps[1] + ps[2] + ps[3];
  sq = pq[0] + pq[1] + pq[2] + pq[3];
  const float mu  = s * (1.0f / 768.0f);
  const float var = sq * (1.0f / 768.0f) - mu * mu;
  const float inv = rsqrtf(var + 1e-5f);
  #pragma unroll
  for (int i = 0; i < 3; ++i) {
    const int c = tid + (i << 8);
    out[base + c] = f2bf((v[i] - mu) * inv * g[c] + b[c]);
  }
}

// ---- GEMM (large): 256x256 tile, BK=64, 8 waves, dbuf 128KB, 4-phase ------
// (round-13/17 structure, best measured). Counted vmcnt(2) once per tile.
// EP 1: gelu->bf16
template<int EP>
__global__ __launch_bounds__(512) void gemm_k(
    const unsigned short* __restrict__ Au, const unsigned short* __restrict__ Btu,
    const float* __restrict__ bias, void* __restrict__ outv,
    const void* __restrict__ residv, void* __restrict__ aux,
    int M, int N, int K, int cgrp) {
  __shared__ __align__(16) __bf16 SMEM[2 * 32768];          // 128 KB
  const __bf16* A  = (const __bf16*)Au;
  const __bf16* Bt = (const __bf16*)Btu;
  const int tid = threadIdx.x;
  const int lane = tid & 63, w = tid >> 6;      // 8 waves
  const int wr = w >> 2, wc = w & 3;            // 2 x 4 wave grid
  const int lr = lane & 15, lg = lane >> 4;
  const int gx = gridDim.x;
  const int bid = blockIdx.y * gx + blockIdx.x;
  const int xcd = bid & 7, idx = bid >> 3;
  const int rpx = gx >> 3;
  const int gsz = rpx * cgrp;
  const int grp = idx / gsz, rem = idx - grp * gsz;
  const int rb = rem / cgrp, cc2 = rem - rb * cgrp + grp * cgrp;
  const int brow = (xcd * rpx + rb) * 256;
  const int bcol = cc2 * 256;

  f32x4 acc[8][4];
  #pragma unroll
  for (int m = 0; m < 8; ++m)
    #pragma unroll
    for (int n = 0; n < 4; ++n) acc[m][n] = (f32x4){0.f, 0.f, 0.f, 0.f};

  const int rrs = lane >> 2;
  const int ccs = (lane & 3) << 3;
  const int csw = ccs ^ ((((lane >> 3) & 3)) << 3);
  const __bf16* sA[4]; const __bf16* sB[4]; int dA[4], dB[4];
  #pragma unroll
  for (int g = 0; g < 4; ++g) {
    const int s = g * 8 + w;
    const int rsrc = (s >> 1) * 16 + rrs;
    const int csrc = (s & 1) * 32 + csw;
    sA[g] = A  + (size_t)(brow + rsrc) * K + csrc;
    sB[g] = Bt + (size_t)(bcol + rsrc) * K + csrc;
    dA[g] = s * 512;
    dB[g] = 16384 + s * 512;
  }

#define STAGE2_(nbb_, k0_, g_) do {                         \
    gload16(sA[g_] + (k0_), &SMEM[(nbb_) + dA[g_]]);        \
    gload16(sB[g_] + (k0_), &SMEM[(nbb_) + dB[g_]]);        \
  } while (0)

  const int rbase = lr * 32 + ((lg << 3) ^ (((lr >> 1) & 3) << 3));

  #pragma unroll
  for (int g = 0; g < 4; ++g) STAGE2_(0, 0, g);

  int cur = 0;
  for (int k0 = 0; k0 < K; k0 += 64, cur ^= 1) {
    const int bb  = cur * 32768;
    const int nbb = (cur ^ 1) * 32768;
    const bool pf = (k0 + 64 < K);
    bf16x8 af0[4][2], af1[4][2], bfr[4][2];
    // P1
    if (pf) {
      STAGE2_(nbb, k0 + 64, 0);
      asm volatile("s_waitcnt vmcnt(2)" ::: "memory");
    } else {
      asm volatile("s_waitcnt vmcnt(0)" ::: "memory");
    }
    __builtin_amdgcn_s_barrier();
    __builtin_amdgcn_sched_barrier(0);
    #pragma unroll
    for (int ml = 0; ml < 4; ++ml)
      #pragma unroll
      for (int kk = 0; kk < 2; ++kk)
        af0[ml][kk] = *(const bf16x8*)(&SMEM[bb + ((wr*8 + ml)*2 + kk)*512 + rbase]);
    #pragma unroll
    for (int n = 0; n < 2; ++n)
      #pragma unroll
      for (int kk = 0; kk < 2; ++kk)
        bfr[n][kk] = *(const bf16x8*)(&SMEM[bb + 16384 + ((wc*4 + n)*2 + kk)*512 + rbase]);
    asm volatile("s_waitcnt lgkmcnt(0)" ::: "memory");
    __builtin_amdgcn_sched_barrier(0);
    __builtin_amdgcn_s_setprio(1);
    #pragma unroll
    for (int ml = 0; ml < 4; ++ml)
      #pragma unroll
      for (int n = 0; n < 2; ++n) {
        acc[ml][n] = __builtin_amdgcn_mfma_f32_16x16x32_bf16(af0[ml][0], bfr[n][0], acc[ml][n], 0, 0, 0);
        acc[ml][n] = __builtin_amdgcn_mfma_f32_16x16x32_bf16(af0[ml][1], bfr[n][1], acc[ml][n], 0, 0, 0);
      }
    __builtin_amdgcn_s_setprio(0);
    __builtin_amdgcn_s_barrier();
    // P2
    #pragma unroll
    for (int n = 2; n < 4; ++n)
      #pragma unroll
      for (int kk = 0; kk < 2; ++kk)
        bfr[n][kk] = *(const bf16x8*)(&SMEM[bb + 16384 + ((wc*4 + n)*2 + kk)*512 + rbase]);
    if (pf) STAGE2_(nbb, k0 + 64, 1);
    asm volatile("s_waitcnt lgkmcnt(0)" ::: "memory");
    __builtin_amdgcn_sched_barrier(0);
    __builtin_amdgcn_s_setprio(1);
    #pragma unroll
    for (int ml = 0; ml < 4; ++ml)
      #pragma unroll
      for (int n = 2; n < 4; ++n) {
        acc[ml][n] = __builtin_amdgcn_mfma_f32_16x16x32_bf16(af0[ml][0], bfr[n][0], acc[ml][n], 0, 0, 0);
        acc[ml][n] = __builtin_amdgcn_mfma_f32_16x16x32_bf16(af0[ml][1], bfr[n][1], acc[ml][n], 0, 0, 0);
      }
    __builtin_amdgcn_s_setprio(0);
    __builtin_amdgcn_s_barrier();
    // P3
    #pragma unroll
    for (int ml = 0; ml < 4; ++ml)
      #pragma unroll
      for (int kk = 0; kk < 2; ++kk)
        af1[ml][kk] = *(const bf16x8*)(&SMEM[bb + ((wr*8 + 4 + ml)*2 + kk)*512 + rbase]);
    if (pf) STAGE2_(nbb, k0 + 64, 2);
    asm volatile("s_waitcnt lgkmcnt(0)" ::: "memory");
    __builtin_amdgcn_sched_barrier(0);
    __builtin_amdgcn_s_setprio(1);
    #pragma unroll
    for (int ml = 0; ml < 4; ++ml)
      #pragma unroll
      for (int n = 0; n < 2; ++n) {
        acc[4+ml][n] = __builtin_amdgcn_mfma_f32_16x16x32_bf16(af1[ml][0], bfr[n][0], acc[4+ml][n], 0, 0, 0);
        acc[4+ml][n] = __builtin_amdgcn_mfma_f32_16x16x32_bf16(af1[ml][1], bfr[n][1], acc[4+ml][n], 0, 0, 0);
      }
    __builtin_amdgcn_s_setprio(0);
    __builtin_amdgcn_s_barrier();
    // P4
    if (pf) STAGE2_(nbb, k0 + 64, 3);
    __builtin_amdgcn_s_setprio(1);
    #pragma unroll
    for (int ml = 0; ml < 4; ++ml)
      #pragma unroll
      for (int n = 2; n < 4; ++n) {
        acc[4+ml][n] = __builtin_amdgcn_mfma_f32_16x16x32_bf16(af1[ml][0], bfr[n][0], acc[4+ml][n], 0, 0, 0);
        acc[4+ml][n] = __builtin_amdgcn_mfma_f32_16x16x32_bf16(af1[ml][1], bfr[n][1], acc[4+ml][n], 0, 0, 0);
      }
    __builtin_amdgcn_s_setprio(0);
    __builtin_amdgcn_s_barrier();
  }
#undef STAGE2_

  // bounce epilogue (EP 0/1 only in this kernel)
  float* Ep = (float*)SMEM + w * 1280;
  #pragma unroll
  for (int m = 0; m < 8; ++m) {
    #pragma unroll
    for (int n = 0; n < 4; ++n) {
      const int col = bcol + wc*64 + n*16 + lr;
      const float bv = bias[col];
      f32x4 st;
      #pragma unroll
      for (int r2 = 0; r2 < 4; ++r2) {
        float v = acc[m][n][r2] + bv;
        if (EP == 1) v = gelu_f(v);
        st[r2] = v;
      }
      *(f32x4*)(Ep + (n*16 + lr) * 20 + lg*4) = st;
    }
    #pragma unroll
    for (int i2 = 0; i2 < 2; ++i2) {
      const int rowL = i2*8 + (lane >> 3);
      const int colL = (lane & 7) * 8;
      const int grow = brow + wr*128 + m*16 + rowL;
      const int gcol = bcol + wc*64 + colL;
      float v[8];
      #pragma unroll
      for (int j = 0; j < 8; ++j) v[j] = Ep[(colL + j) * 20 + rowL];
      bf16x8 ov;
      #pragma unroll
      for (int j = 0; j < 8; ++j) ov[j] = (__bf16)v[j];
      *(bf16x8*)((__bf16*)outv + (size_t)grow * N + gcol) = ov;
    }
  }
}

// ---- GEMM (mid): 128x128 tile, BK=64, 4 waves, 64KB dbuf, 2-phase ---------
// 32 MFMA/iter, counted vmcnt(4); 2 blocks/CU.
// EP 2: +resid(f32)->bf16 | 3: gelu+resid(bf16)->f32 | 5: QKV split store
template<int EP>
__global__ __launch_bounds__(256) void gemm_m(
    const unsigned short* __restrict__ Au, const unsigned short* __restrict__ Btu,
    const float* __restrict__ bias, void* __restrict__ outv,
    const void* __restrict__ residv, void* __restrict__ aux,
    int M, int N, int K, int cgrp) {
  __shared__ __align__(16) __bf16 SMEM[2 * 16384];          // 64 KB
  const __bf16* A  = (const __bf16*)Au;
  const __bf16* Bt = (const __bf16*)Btu;
  const int tid = threadIdx.x;
  const int lane = tid & 63, w = tid >> 6;      // 4 waves
  const int wr = w >> 1, wc = w & 1;            // 2 x 2 wave grid
  const int lr = lane & 15, lg = lane >> 4;
  const int gx = gridDim.x;
  const int bid = blockIdx.y * gx + blockIdx.x;
  const int xcd = bid & 7, idx = bid >> 3;
  const int rpx = gx >> 3;
  const int gsz = rpx * cgrp;
  const int grp = idx / gsz, rem = idx - grp * gsz;
  const int rb = rem / cgrp, cc2 = rem - rb * cgrp + grp * cgrp;
  const int brow = (xcd * rpx + rb) * 128;
  const int bcol = cc2 * 128;

  f32x4 acc[4][4];
  #pragma unroll
  for (int m = 0; m < 4; ++m)
    #pragma unroll
    for (int n = 0; n < 4; ++n) acc[m][n] = (f32x4){0.f, 0.f, 0.f, 0.f};

  const int rrs = lane >> 2;
  const int ccs = (lane & 3) << 3;
  const int csw = ccs ^ ((((lane >> 3) & 3)) << 3);   // inverse swizzle
  const __bf16* sA[4]; const __bf16* sB[4]; int dA[4], dB[4];
  #pragma unroll
  for (int g = 0; g < 4; ++g) {
    const int s = g * 4 + w;                    // 0..15
    const int rsrc = (s >> 1) * 16 + rrs;
    const int csrc = (s & 1) * 32 + csw;
    sA[g] = A  + (size_t)(brow + rsrc) * K + csrc;
    sB[g] = Bt + (size_t)(bcol + rsrc) * K + csrc;
    dA[g] = s * 512;
    dB[g] = 8192 + s * 512;
  }

#define STAGEM_(nbb_, k0_, g_) do {                         \
    gload16(sA[g_] + (k0_), &SMEM[(nbb_) + dA[g_]]);        \
    gload16(sB[g_] + (k0_), &SMEM[(nbb_) + dB[g_]]);        \
  } while (0)

  const int rbase = lr * 32 + ((lg << 3) ^ (((lr >> 1) & 3) << 3));

  #pragma unroll
  for (int g = 0; g < 4; ++g) STAGEM_(0, 0, g);   // prologue: tile 0

  int cur = 0;
  for (int k0 = 0; k0 < K; k0 += 64, cur ^= 1) {
    const int bb  = cur * 16384;
    const int nbb = (cur ^ 1) * 16384;
    const bool pf = (k0 + 64 < K);
    bf16x8 af[4][2], bfr[4][2];
    // P1
    if (pf) {
      STAGEM_(nbb, k0 + 64, 0);
      STAGEM_(nbb, k0 + 64, 1);
      asm volatile("s_waitcnt vmcnt(4)" ::: "memory");
    } else {
      asm volatile("s_waitcnt vmcnt(0)" ::: "memory");
    }
    __builtin_amdgcn_s_barrier();
    __builtin_amdgcn_sched_barrier(0);
    #pragma unroll
    for (int ml = 0; ml < 4; ++ml)
      #pragma unroll
      for (int kk = 0; kk < 2; ++kk)
        af[ml][kk] = *(const bf16x8*)(&SMEM[bb + ((wr*4 + ml)*2 + kk)*512 + rbase]);
    #pragma unroll
    for (int n = 0; n < 2; ++n)
      #pragma unroll
      for (int kk = 0; kk < 2; ++kk)
        bfr[n][kk] = *(const bf16x8*)(&SMEM[bb + 8192 + ((wc*4 + n)*2 + kk)*512 + rbase]);
    asm volatile("s_waitcnt lgkmcnt(0)" ::: "memory");
    __builtin_amdgcn_sched_barrier(0);
    __builtin_amdgcn_s_setprio(1);
    #pragma unroll
    for (int ml = 0; ml < 4; ++ml)
      #pragma unroll
      for (int n = 0; n < 2; ++n) {
        acc[ml][n] = __builtin_amdgcn_mfma_f32_16x16x32_bf16(af[ml][0], bfr[n][0], acc[ml][n], 0, 0, 0);
        acc[ml][n] = __builtin_amdgcn_mfma_f32_16x16x32_bf16(af[ml][1], bfr[n][1], acc[ml][n], 0, 0, 0);
      }
    __builtin_amdgcn_s_setprio(0);
    __builtin_amdgcn_s_barrier();
    // P2
    #pragma unroll
    for (int n = 2; n < 4; ++n)
      #pragma unroll
      for (int kk = 0; kk < 2; ++kk)
        bfr[n][kk] = *(const bf16x8*)(&SMEM[bb + 8192 + ((wc*4 + n)*2 + kk)*512 + rbase]);
    if (pf) {
      STAGEM_(nbb, k0 + 64, 2);
      STAGEM_(nbb, k0 + 64, 3);
    }
    asm volatile("s_waitcnt lgkmcnt(0)" ::: "memory");
    __builtin_amdgcn_sched_barrier(0);
    __builtin_amdgcn_s_setprio(1);
    #pragma unroll
    for (int ml = 0; ml < 4; ++ml)
      #pragma unroll
      for (int n = 2; n < 4; ++n) {
        acc[ml][n] = __builtin_amdgcn_mfma_f32_16x16x32_bf16(af[ml][0], bfr[n][0], acc[ml][n], 0, 0, 0);
        acc[ml][n] = __builtin_amdgcn_mfma_f32_16x16x32_bf16(af[ml][1], bfr[n][1], acc[ml][n], 0, 0, 0);
      }
    __builtin_amdgcn_s_setprio(0);
    __builtin_amdgcn_s_barrier();
  }
#undef STAGEM_

  const int seg = (EP == 5) ? (bcol / 768) : 0;     // block-uniform (768=6*128)
  unsigned short* qkvp = nullptr;
  if (EP == 5)
    qkvp = (seg == 0) ? (unsigned short*)outv
         : (seg == 1) ? (unsigned short*)residv : (unsigned short*)aux;

  if (EP == 5 && seg == 2) {
    // v^T scatter store (per batch): vt[(b*768 + colLv)*1024 + token]
    #pragma unroll
    for (int n = 0; n < 4; ++n) {
      const int col = bcol + wc*64 + n*16 + lr;
      const float bv = bias[col];
      const int colLv = col - 1536;
      #pragma unroll
      for (int m = 0; m < 4; ++m) {
        const int row0 = brow + wr*64 + m*16 + lg*4;
        #pragma unroll
        for (int r2 = 0; r2 < 4; ++r2) {
          const int gr = row0 + r2;
          qkvp[(((size_t)(gr >> 10) * D_MODEL + colLv) << 10) + (gr & 1023)] =
              f2bf(acc[m][n][r2] + bv);
        }
      }
    }
  } else {
    // coalesced bounce epilogue: per-wave f32 tile [64 col][20 row]
    float* Ep = (float*)SMEM + w * 1280;
    #pragma unroll
    for (int p = 0; p < 4; ++p) {
      #pragma unroll
      for (int n = 0; n < 4; ++n) {
        const int col = bcol + wc*64 + n*16 + lr;
        const float bv = bias[col];
        f32x4 st;
        #pragma unroll
        for (int r2 = 0; r2 < 4; ++r2) {
          float v = acc[p][n][r2] + bv;
          if (EP == 3) v = gelu_f(v);
          st[r2] = v;
        }
        *(f32x4*)(Ep + (n*16 + lr) * 20 + lg*4) = st;
      }
      #pragma unroll
      for (int i2 = 0; i2 < 2; ++i2) {
        const int rowL = i2*8 + (lane >> 3);
        const int colL = (lane & 7) * 8;
        const int grow = brow + wr*64 + p*16 + rowL;
        const int gcol = bcol + wc*64 + colL;
        float v[8];
        #pragma unroll
        for (int j = 0; j < 8; ++j) v[j] = Ep[(colL + j) * 20 + rowL];
        const size_t o = (size_t)grow * N + gcol;
        if (EP == 3) {                 // gelu applied; + resid(bf16) -> f32
          const bf16x8 rv = *(const bf16x8*)((const __bf16*)residv + o);
          float* op = (float*)outv + o;
          float4 o0, o1;
          o0.x = v[0] + (float)rv[0]; o0.y = v[1] + (float)rv[1];
          o0.z = v[2] + (float)rv[2]; o0.w = v[3] + (float)rv[3];
          o1.x = v[4] + (float)rv[4]; o1.y = v[5] + (float)rv[5];
          o1.z = v[6] + (float)rv[6]; o1.w = v[7] + (float)rv[7];
          *(float4*)op = o0; *(float4*)(op + 4) = o1;
        } else if (EP == 2) {          // + resid(f32) -> bf16
          const float* rp = (const float*)residv + o;
          const float4 r0 = *(const float4*)rp, r1 = *(const float4*)(rp + 4);
          bf16x8 ov;
          ov[0] = (__bf16)(v[0] + r0.x); ov[1] = (__bf16)(v[1] + r0.y);
          ov[2] = (__bf16)(v[2] + r0.z); ov[3] = (__bf16)(v[3] + r0.w);
          ov[4] = (__bf16)(v[4] + r1.x); ov[5] = (__bf16)(v[5] + r1.y);
          ov[6] = (__bf16)(v[6] + r1.z); ov[7] = (__bf16)(v[7] + r1.w);
          *(bf16x8*)((__bf16*)outv + o) = ov;
        } else {                       // EP 5, seg 0/1: q/k 768-wide dest
          bf16x8 ov;
          #pragma unroll
          for (int j = 0; j < 8; ++j) ov[j] = (__bf16)v[j];
          *(bf16x8*)((__bf16*)qkvp + (size_t)grow * 768 + (gcol - seg * 768)) = ov;
        }
      }
    }
  }
}

// ---------------- flash attention: 768 blocks, XCD-sequential bh -----------
__global__ __launch_bounds__(512) void attn_k(
    const unsigned short* qu, const unsigned short* __restrict__ ku,
    const unsigned short* __restrict__ vtu, unsigned short* attn) {
  __shared__ __align__(16) __bf16 Kl[64][72];
  __shared__ __align__(16) __bf16 Vl[64][72];
  __shared__ __align__(16) __bf16 Pl[8][16][72];
  const __bf16* qg  = (const __bf16*)qu;
  const __bf16* kg  = (const __bf16*)ku;
  const __bf16* vtg = (const __bf16*)vtu;
  const int bid = blockIdx.x;
  const int xcd = bid & 7, idx = bid >> 3;
  const int bh = xcd * 24 + (idx >> 2);
  const int b = bh / 12, h = bh % 12;
  const int q0 = (idx & 3) * 256;
  const int tid = threadIdx.x, lane = tid & 63, w = tid >> 6;
  const int lr = lane & 15, lg = lane >> 4;
  const float scale = 0.03608439182435161f; // 1/sqrt(768)

  bf16x8 qa[2][2];
  #pragma unroll
  for (int g = 0; g < 2; ++g) {
    const int qrow = b * T_SEQ + q0 + w * 32 + g * 16 + lr;
    const __bf16* qp = qg + (size_t)qrow * D_MODEL + h * 64 + lg * 8;
    qa[g][0] = *(const bf16x8*)(qp);
    qa[g][1] = *(const bf16x8*)(qp + 32);
  }

  const __bf16* kb = kg  + (size_t)b * T_SEQ * D_MODEL + h * 64;
  const __bf16* vb = vtg + ((size_t)b * D_MODEL + h * 64) * T_SEQ;

  f32x4 o[2][4];
  float m_run[2] = {-1e30f, -1e30f}, l_run[2] = {0.f, 0.f};
  #pragma unroll
  for (int g = 0; g < 2; ++g)
    #pragma unroll
    for (int m = 0; m < 4; ++m) o[g][m] = (f32x4){0.f, 0.f, 0.f, 0.f};

  for (int kv0 = 0; kv0 < T_SEQ; kv0 += 64) {
    __syncthreads();
    {
      const int r = tid >> 3, c = (tid & 7) << 3;
      *(bf16x8*)(&Kl[r][c]) = *(const bf16x8*)(kb + (size_t)(kv0 + r) * D_MODEL + c);
      *(bf16x8*)(&Vl[r][c]) = *(const bf16x8*)(vb + (size_t)r * T_SEQ + kv0 + c);
    }
    __syncthreads();

    #pragma unroll
    for (int g = 0; g < 2; ++g) {
      f32x4 s[4];
      __builtin_amdgcn_s_setprio(1);
      #pragma unroll
      for (int m = 0; m < 4; ++m) {
        s[m] = (f32x4){0.f, 0.f, 0.f, 0.f};
        const bf16x8 kf0 = *(const bf16x8*)(&Kl[m*16 + lr][lg*8]);
        const bf16x8 kf1 = *(const bf16x8*)(&Kl[m*16 + lr][32 + lg*8]);
        s[m] = __builtin_amdgcn_mfma_f32_16x16x32_bf16(kf0, qa[g][0], s[m], 0, 0, 0);
        s[m] = __builtin_amdgcn_mfma_f32_16x16x32_bf16(kf1, qa[g][1], s[m], 0, 0, 0);
      }
      __builtin_amdgcn_s_setprio(0);
      float sv[4][4], tm = -1e30f;
      #pragma unroll
      for (int m = 0; m < 4; ++m)
        #pragma unroll
        for (int r = 0; r < 4; ++r) {
          sv[m][r] = s[m][r] * scale;
          tm = fmaxf(tm, sv[m][r]);
        }
      tm = fmaxf(tm, __shfl_xor(tm, 16));
      tm = fmaxf(tm, __shfl_xor(tm, 32));
      const float mn = fmaxf(m_run[g], tm);
      const float sc = __expf(m_run[g] - mn);
      float ts = 0.f;
      bf16x4 pk[4];
      #pragma unroll
      for (int m = 0; m < 4; ++m)
        #pragma unroll
        for (int r = 0; r < 4; ++r) {
          const float pp = __expf(sv[m][r] - mn);
          ts += pp;
          pk[m][r] = (__bf16)pp;
        }
      ts += __shfl_xor(ts, 16);
      ts += __shfl_xor(ts, 32);
      l_run[g] = l_run[g] * sc + ts;
      m_run[g] = mn;
      #pragma unroll
      for (int m = 0; m < 4; ++m)
        #pragma unroll
        for (int r = 0; r < 4; ++r) o[g][m][r] *= sc;
      #pragma unroll
      for (int m = 0; m < 4; ++m)
        *(bf16x4*)(&Pl[w][lr][16*m + 4*lg]) = pk[m];
      const bf16x8 pf0 = *(const bf16x8*)(&Pl[w][lr][lg*8]);
      const bf16x8 pf1 = *(const bf16x8*)(&Pl[w][lr][32 + lg*8]);
      __builtin_amdgcn_s_setprio(1);
      #pragma unroll
      for (int m = 0; m < 4; ++m) {
        const bf16x8 vf0 = *(const bf16x8*)(&Vl[m*16 + lr][lg*8]);
        const bf16x8 vf1 = *(const bf16x8*)(&Vl[m*16 + lr][32 + lg*8]);
        o[g][m] = __builtin_amdgcn_mfma_f32_16x16x32_bf16(vf0, pf0, o[g][m], 0, 0, 0);
        o[g][m] = __builtin_amdgcn_mfma_f32_16x16x32_bf16(vf1, pf1, o[g][m], 0, 0, 0);
      }
      __builtin_amdgcn_s_setprio(0);
    }
  }

  #pragma unroll
  for (int g = 0; g < 2; ++g) {
    const float inv = 1.0f / l_run[g];
    const int qrow = b * T_SEQ + q0 + w * 32 + g * 16 + lr;
    unsigned short* op = attn + (size_t)qrow * D_MODEL + h * 64;
    #pragma unroll
    for (int m = 0; m < 4; ++m) {
      bf16x4 ov;
      #pragma unroll
      for (int r = 0; r < 4; ++r) ov[r] = (__bf16)(o[g][m][r] * inv);
      *(bf16x4*)(op + 16*m + 4*lg) = ov;
    }
  }
}

// ---------------------------------------------------------------------------
extern "C" void kernel_launch(void* const* d_in, const int* in_sizes, int n_in,
                              void* d_out, int out_size, void* d_ws, size_t ws_size,
                              hipStream_t stream) {
  const float* x   = (const float*)d_in[0];
  const float* Wq  = (const float*)d_in[1];
  const float* bq  = (const float*)d_in[2];
  const float* Wk  = (const float*)d_in[3];
  const float* bk  = (const float*)d_in[4];
  const float* Wv  = (const float*)d_in[5];
  const float* bv  = (const float*)d_in[6];
  const float* Wo  = (const float*)d_in[7];
  const float* bo  = (const float*)d_in[8];
  const float* g1  = (const float*)d_in[9];
  const float* bt1 = (const float*)d_in[10];
  const float* g2  = (const float*)d_in[11];
  const float* bt2 = (const float*)d_in[12];
  const float* W1  = (const float*)d_in[13];
  const float* bb1 = (const float*)d_in[14];
  const float* W2  = (const float*)d_in[15];
  const float* bb2 = (const float*)d_in[16];

  const size_t SZ = (size_t)M_ROWS * D_MODEL * 2;   // 25,165,824
  char* wp = (char*)d_ws;
  unsigned short* wqkvT = (unsigned short*)wp; wp += (size_t)2304 * 768 * 2;
  unsigned short* woT   = (unsigned short*)wp; wp += (size_t)768 * 768 * 2;
  unsigned short* w1T   = (unsigned short*)wp; wp += (size_t)768 * 3072 * 2;
  unsigned short* w2T   = (unsigned short*)wp; wp += (size_t)768 * 3072 * 2;
  float*          bqkv  = (float*)wp;          wp += ((size_t)2304 * 4 + 255) & ~(size_t)255;
  unsigned short* kbuf  = (unsigned short*)wp; wp += SZ;   // k -> res2
  unsigned short* vtb   = (unsigned short*)wp;             // vT -> hid
  unsigned short* res2  = kbuf;
  unsigned short* hid   = vtb;
  const size_t avail = ws_size - (size_t)(wp - (char*)d_ws);
  const int nch = (avail >= (size_t)M_ROWS * MLP_DIM * 2) ? 1
                : (avail >= (size_t)(M_ROWS / 2) * MLP_DIM * 2) ? 2 : 4;

  unsigned short* qd = (unsigned short*)d_out;             // bf16 lo half
  unsigned short* h1 = qd + (size_t)M_ROWS * D_MODEL;      // bf16 hi half
  unsigned short* h2 = h1;

  const dim3 tb(32, 8, 1);
  wtr_k<<<dim3(24, 24), tb, 0, stream>>>(Wq, wqkvT, 768, 768);
  wtr_k<<<dim3(24, 24), tb, 0, stream>>>(Wk, wqkvT + (size_t)768 * 768, 768, 768);
  wtr_k<<<dim3(24, 24), tb, 0, stream>>>(Wv, wqkvT + (size_t)1536 * 768, 768, 768);
  wtr_k<<<dim3(24, 24), tb, 0, stream>>>(Wo, woT, 768, 768);
  wtr_k<<<dim3(96, 24), tb, 0, stream>>>(W1, w1T, 768, 3072);
  wtr_k<<<dim3(24, 96), tb, 0, stream>>>(W2, w2T, 3072, 768);
  bcat_k<<<3, 256, 0, stream>>>(bq, bk, bv, bqkv);

  ln_k<1><<<M_ROWS, 256, 0, stream>>>(x, g1, bt1, h1);

  gemm_m<5><<<dim3(128, 18), 256, 0, stream>>>(h1, wqkvT, bqkv, qd, kbuf, vtb,
                                               M_ROWS, 2304, 768, 9);

  attn_k<<<dim3(768), 512, 0, stream>>>(qd, kbuf, vtb, qd);

  gemm_m<2><<<dim3(128, 6), 256, 0, stream>>>(qd, woT, bo, res2, x, nullptr,
                                              M_ROWS, 768, 768, 3);

  ln_k<0><<<M_ROWS, 256, 0, stream>>>(res2, g2, bt2, h2);

  const int CH = M_ROWS / nch;
  for (int c = 0; c < nch; ++c) {
    const size_t ro = (size_t)c * CH;
    gemm_k<1><<<dim3(CH / 256, 12), 512, 0, stream>>>(h2 + ro * 768, w1T, bb1,
        hid, nullptr, nullptr, CH, 3072, 768, 6);
    gemm_m<3><<<dim3(CH / 128, 6), 256, 0, stream>>>(hid, w2T, bb2,
        (float*)d_out + ro * 768, res2 + ro * 768, nullptr, CH, 768, 3072, 3);
  }
}